// Round 1
// baseline (1233.057 us; speedup 1.0000x reference)
//
#include <hip/hip_runtime.h>
#include <hip/hip_bf16.h>

#define D_HID 2048
#define F_EXP 1408
#define E_NUM 8
#define FS_SH 2816
#define T_TOK 2048

typedef __attribute__((ext_vector_type(8))) short bf16x8;
typedef __attribute__((ext_vector_type(4))) float f32x4;
typedef __attribute__((ext_vector_type(4))) unsigned int u32x4;
typedef __attribute__((ext_vector_type(4))) unsigned short u16x4;

__device__ __forceinline__ unsigned short f2bf(float f){
  unsigned u = __float_as_uint(f);
  u += 0x7fffu + ((u >> 16) & 1u);          // RNE
  return (unsigned short)(u >> 16);
}

// ---------------- x fp32 -> bf16 ----------------
__global__ void convert_x_kernel(const float* __restrict__ x, unsigned short* __restrict__ xb){
  const int i = blockIdx.x * blockDim.x + threadIdx.x;   // one float4 per thread, exact grid
  float4 v = ((const float4*)x)[i];
  u16x4 h;
  h[0]=f2bf(v.x); h[1]=f2bf(v.y); h[2]=f2bf(v.z); h[3]=f2bf(v.w);
  ((u16x4*)xb)[i] = h;
}

// ---------------- router: logits, softmax, top-2 ----------------
__global__ __launch_bounds__(64) void router_kernel(const float* __restrict__ x,
                                                    const float* __restrict__ Wr,
                                                    int* __restrict__ topk_e,
                                                    float* __restrict__ topk_w){
  const int t = blockIdx.x;
  const int lane = threadIdx.x;
  const float* xt = x + (size_t)t * D_HID;
  float acc[E_NUM];
  #pragma unroll
  for (int e=0;e<E_NUM;e++) acc[e]=0.f;
  for (int d=lane; d<D_HID; d+=64){
    const float xv = xt[d];
    #pragma unroll
    for (int e=0;e<E_NUM;e++) acc[e] += xv * Wr[e*D_HID + d];
  }
  #pragma unroll
  for (int e=0;e<E_NUM;e++){
    #pragma unroll
    for (int off=32; off>0; off>>=1) acc[e] += __shfl_xor(acc[e], off);
  }
  if (lane==0){
    float m = acc[0];
    #pragma unroll
    for (int e=1;e<E_NUM;e++) m = fmaxf(m, acc[e]);
    float p[E_NUM]; float s = 0.f;
    #pragma unroll
    for (int e=0;e<E_NUM;e++){ p[e] = expf(acc[e]-m); s += p[e]; }
    const float inv = 1.f/s;
    int i0=0; float b0=p[0];
    #pragma unroll
    for (int e=1;e<E_NUM;e++) if (p[e] > b0){ b0=p[e]; i0=e; }
    int i1=-1; float b1=-1.f;
    #pragma unroll
    for (int e=0;e<E_NUM;e++) if (e!=i0 && p[e] > b1){ b1=p[e]; i1=e; }
    topk_e[t*2+0]=i0; topk_e[t*2+1]=i1;
    topk_w[t*2+0]=b0*inv; topk_w[t*2+1]=b1*inv;
  }
}

// ---------------- deterministic expert-grouped list build ----------------
__global__ __launch_bounds__(64) void build_lists_kernel(const int* __restrict__ topk_e,
                                                         const float* __restrict__ topk_w,
                                                         int* __restrict__ cnt, int* __restrict__ offs,
                                                         int* __restrict__ assign_token,
                                                         float* __restrict__ assign_w,
                                                         int* __restrict__ token_slot){
  const int lane = threadIdx.x;
  int c = 0;
  if (lane < E_NUM){
    for (int t=0;t<T_TOK*2;t++) c += (topk_e[t]==lane) ? 1 : 0;
  }
  int off = 0;
  for (int i=0;i<E_NUM;i++){ const int ci = __shfl(c, i); if (i < lane) off += ci; }
  if (lane < E_NUM){
    cnt[lane]=c; offs[lane]=off;
    int pos = off;
    for (int t=0;t<T_TOK;t++){
      #pragma unroll
      for (int k=0;k<2;k++){
        if (topk_e[t*2+k]==lane){
          assign_token[pos]=t; assign_w[pos]=topk_w[t*2+k]; token_slot[t*2+k]=pos; pos++;
        }
      }
    }
  }
}

// ---------------- fused gate+up GEMM: H = silu(A Wg^T) * (A Wu^T) ----------------
// A: bf16 [*,K]; W*: fp32 [ (E,)N,K ]; Hout: bf16 [*,N].  BM=BN=128, BK=64, 256 thr / 4 waves.
template<int GATHER>
__global__ __launch_bounds__(256,1) void gemm_gateup(
    const unsigned short* __restrict__ A,
    const float* __restrict__ Wg_all,
    const float* __restrict__ Wu_all,
    unsigned short* __restrict__ Hout,
    const int* __restrict__ cnt, const int* __restrict__ offs,
    const int* __restrict__ assign_token,
    int N, int K)
{
  __shared__ __align__(16) char As[128*128];
  __shared__ __align__(16) char Bg[128*128];
  __shared__ __align__(16) char Bu[128*128];

  const int tid  = threadIdx.x;
  const int lane = tid & 63;
  const int wave = tid >> 6;
  const int wr = wave >> 1, wc = wave & 1;
  const int nt = blockIdx.x;

  int rowbase_out, valid, rowmax = 0;
  const float *Wgp, *Wup;
  if (GATHER){
    const int e  = blockIdx.y >> 4;
    const int mt = blockIdx.y & 15;
    const int c  = cnt[e];
    if (mt*128 >= c) return;
    const int o = offs[e];
    rowbase_out = o + mt*128;
    valid = c - mt*128; if (valid > 128) valid = 128;
    rowmax = o + c - 1;
    Wgp = Wg_all + (size_t)e * (size_t)N * (size_t)K;
    Wup = Wu_all + (size_t)e * (size_t)N * (size_t)K;
  } else {
    rowbase_out = blockIdx.y * 128;
    valid = 128;
    Wgp = Wg_all; Wup = Wu_all;
  }

  f32x4 accg[4][4], accu[4][4];
  const f32x4 z = {0.f,0.f,0.f,0.f};
  #pragma unroll
  for (int m=0;m<4;m++)
    #pragma unroll
    for (int n=0;n<4;n++){ accg[m][n]=z; accu[m][n]=z; }

  // A staging: pre-swizzled global source so linear global_load_lds dest + swizzled read agree
  const char* asrc[4];
  #pragma unroll
  for (int p=0;p<4;p++){
    const int c   = ((wave*4 + p) << 6) + lane;
    const int row = c >> 3;
    const int cb  = (c & 7) << 4;
    const int srccol = cb ^ ((row & 7) << 4);
    size_t grow;
    if (GATHER){
      int idx = rowbase_out + row;
      if (idx > rowmax) idx = rowmax;
      grow = (size_t)assign_token[idx];
    } else {
      grow = (size_t)(rowbase_out + row);
    }
    asrc[p] = (const char*)(A + grow * (size_t)K) + srccol;
  }
  const int brow = tid >> 1;
  const int hc   = (tid & 1) * 32;
  const int bswz = (brow & 7) << 4;
  const float* sg0 = Wgp + (size_t)(nt*128 + brow) * K + hc;
  const float* su0 = Wup + (size_t)(nt*128 + brow) * K + hc;

  const int nK = K >> 6;
  for (int kt = 0; kt < nK; ++kt){
    __syncthreads();
    #pragma unroll
    for (int p=0;p<4;p++){
      __builtin_amdgcn_global_load_lds(
        (const __attribute__((address_space(1))) void*)(asrc[p] + (size_t)kt*128),
        (__attribute__((address_space(3))) void*)(As + (wave*4 + p)*1024),
        16, 0, 0);
    }
    {
      const float* sg = sg0 + (size_t)kt*64;
      const float* su = su0 + (size_t)kt*64;
      unsigned short hg[32], hu[32];
      #pragma unroll
      for (int j=0;j<8;j++){
        float4 v = ((const float4*)sg)[j];
        hg[j*4+0]=f2bf(v.x); hg[j*4+1]=f2bf(v.y); hg[j*4+2]=f2bf(v.z); hg[j*4+3]=f2bf(v.w);
      }
      #pragma unroll
      for (int j=0;j<8;j++){
        float4 v = ((const float4*)su)[j];
        hu[j*4+0]=f2bf(v.x); hu[j*4+1]=f2bf(v.y); hu[j*4+2]=f2bf(v.z); hu[j*4+3]=f2bf(v.w);
      }
      #pragma unroll
      for (int cc=0; cc<4; cc++){
        const int colbyte = hc*2 + cc*16;
        const int dst = brow*128 + (colbyte ^ bswz);
        *(u32x4*)(Bg + dst) = *(const u32x4*)&hg[cc*8];
        *(u32x4*)(Bu + dst) = *(const u32x4*)&hu[cc*8];
      }
    }
    __syncthreads();
    #pragma unroll
    for (int kk=0;kk<2;kk++){
      const int kb = kk*64 + ((lane >> 4) << 4);
      bf16x8 a[4], bg[4], bu[4];
      #pragma unroll
      for (int m=0;m<4;m++){
        const int r = wr*64 + m*16 + (lane & 15);
        a[m] = *(const bf16x8*)(As + r*128 + (kb ^ ((r & 7) << 4)));
      }
      #pragma unroll
      for (int n=0;n<4;n++){
        const int r = wc*64 + n*16 + (lane & 15);
        const int ofs = r*128 + (kb ^ ((r & 7) << 4));
        bg[n] = *(const bf16x8*)(Bg + ofs);
        bu[n] = *(const bf16x8*)(Bu + ofs);
      }
      #pragma unroll
      for (int m=0;m<4;m++)
        #pragma unroll
        for (int n=0;n<4;n++){
          accg[m][n] = __builtin_amdgcn_mfma_f32_16x16x32_bf16(a[m], bg[n], accg[m][n], 0,0,0);
          accu[m][n] = __builtin_amdgcn_mfma_f32_16x16x32_bf16(a[m], bu[n], accu[m][n], 0,0,0);
        }
    }
  }
  const int colbase = nt*128 + wc*64;
  #pragma unroll
  for (int m=0;m<4;m++){
    #pragma unroll
    for (int r=0;r<4;r++){
      const int rr = wr*64 + m*16 + ((lane >> 4) << 2) + r;
      if (rr < valid){
        unsigned short* orow = Hout + (size_t)(rowbase_out + rr) * N;
        #pragma unroll
        for (int n=0;n<4;n++){
          const int col = colbase + n*16 + (lane & 15);
          const float g = accg[m][n][r];
          const float u = accu[m][n][r];
          const float h = (g / (1.f + __expf(-g))) * u;
          orow[col] = f2bf(h);
        }
      }
    }
  }
}

// ---------------- down GEMM: Out = (A Wd^T) [* row weight] ----------------
template<int ROUTED>
__global__ __launch_bounds__(256,1) void gemm_down(
    const unsigned short* __restrict__ A,   // bf16 [*,K]
    const float* __restrict__ Wd_all,       // fp32 [(E,)N,K]
    float* __restrict__ Out,                // fp32 [*,N]
    const int* __restrict__ cnt, const int* __restrict__ offs,
    const float* __restrict__ assign_w,
    int N, int K)
{
  __shared__ __align__(16) char As[128*128];
  __shared__ __align__(16) char Bs[128*128];

  const int tid  = threadIdx.x;
  const int lane = tid & 63;
  const int wave = tid >> 6;
  const int wr = wave >> 1, wc = wave & 1;
  const int nt = blockIdx.x;

  int rowbase_out, valid, rowmax = 0;
  const float *Wp;
  if (ROUTED){
    const int e  = blockIdx.y >> 4;
    const int mt = blockIdx.y & 15;
    const int c  = cnt[e];
    if (mt*128 >= c) return;
    const int o = offs[e];
    rowbase_out = o + mt*128;
    valid = c - mt*128; if (valid > 128) valid = 128;
    rowmax = o + c - 1;
    Wp = Wd_all + (size_t)e * (size_t)N * (size_t)K;
  } else {
    rowbase_out = blockIdx.y * 128;
    valid = 128;
    Wp = Wd_all;
  }

  f32x4 acc[4][4];
  const f32x4 z = {0.f,0.f,0.f,0.f};
  #pragma unroll
  for (int m=0;m<4;m++)
    #pragma unroll
    for (int n=0;n<4;n++) acc[m][n]=z;

  const char* asrc[4];
  #pragma unroll
  for (int p=0;p<4;p++){
    const int c   = ((wave*4 + p) << 6) + lane;
    const int row = c >> 3;
    const int cb  = (c & 7) << 4;
    const int srccol = cb ^ ((row & 7) << 4);
    int idx = rowbase_out + row;
    if (ROUTED && idx > rowmax) idx = rowmax;
    asrc[p] = (const char*)(A + (size_t)idx * (size_t)K) + srccol;
  }
  const int brow = tid >> 1;
  const int hc   = (tid & 1) * 32;
  const int bswz = (brow & 7) << 4;
  const float* sb0 = Wp + (size_t)(nt*128 + brow) * K + hc;

  const int nK = K >> 6;
  for (int kt = 0; kt < nK; ++kt){
    __syncthreads();
    #pragma unroll
    for (int p=0;p<4;p++){
      __builtin_amdgcn_global_load_lds(
        (const __attribute__((address_space(1))) void*)(asrc[p] + (size_t)kt*128),
        (__attribute__((address_space(3))) void*)(As + (wave*4 + p)*1024),
        16, 0, 0);
    }
    {
      const float* sb = sb0 + (size_t)kt*64;
      unsigned short hb[32];
      #pragma unroll
      for (int j=0;j<8;j++){
        float4 v = ((const float4*)sb)[j];
        hb[j*4+0]=f2bf(v.x); hb[j*4+1]=f2bf(v.y); hb[j*4+2]=f2bf(v.z); hb[j*4+3]=f2bf(v.w);
      }
      #pragma unroll
      for (int cc=0; cc<4; cc++){
        const int colbyte = hc*2 + cc*16;
        const int dst = brow*128 + (colbyte ^ bswz);
        *(u32x4*)(Bs + dst) = *(const u32x4*)&hb[cc*8];
      }
    }
    __syncthreads();
    #pragma unroll
    for (int kk=0;kk<2;kk++){
      const int kb = kk*64 + ((lane >> 4) << 4);
      bf16x8 a[4], b[4];
      #pragma unroll
      for (int m=0;m<4;m++){
        const int r = wr*64 + m*16 + (lane & 15);
        a[m] = *(const bf16x8*)(As + r*128 + (kb ^ ((r & 7) << 4)));
      }
      #pragma unroll
      for (int n=0;n<4;n++){
        const int r = wc*64 + n*16 + (lane & 15);
        b[n] = *(const bf16x8*)(Bs + r*128 + (kb ^ ((r & 7) << 4)));
      }
      #pragma unroll
      for (int m=0;m<4;m++)
        #pragma unroll
        for (int n=0;n<4;n++)
          acc[m][n] = __builtin_amdgcn_mfma_f32_16x16x32_bf16(a[m], b[n], acc[m][n], 0,0,0);
    }
  }
  const int colbase = nt*128 + wc*64;
  #pragma unroll
  for (int m=0;m<4;m++){
    #pragma unroll
    for (int r=0;r<4;r++){
      const int rr = wr*64 + m*16 + ((lane >> 4) << 2) + r;
      if (rr < valid){
        float w = 1.f;
        if (ROUTED) w = assign_w[rowbase_out + rr];
        float* orow = Out + (size_t)(rowbase_out + rr) * N;
        #pragma unroll
        for (int n=0;n<4;n++){
          const int col = colbase + n*16 + (lane & 15);
          orow[col] = acc[m][n][r] * w;
        }
      }
    }
  }
}

// ---------------- combine: out += y[slot0] + y[slot1] ----------------
__global__ void combine_kernel(float* __restrict__ out, const float* __restrict__ y,
                               const int* __restrict__ token_slot){
  const int i  = blockIdx.x * blockDim.x + threadIdx.x;   // float4 index
  const int t  = i >> 9;                                   // 512 float4 per row (D=2048)
  const int r4 = i & 511;
  const int s0 = token_slot[t*2+0];
  const int s1 = token_slot[t*2+1];
  const float4 a = ((const float4*)(y + (size_t)s0 * D_HID))[r4];
  const float4 b = ((const float4*)(y + (size_t)s1 * D_HID))[r4];
  float4 o = ((float4*)out)[i];
  o.x += a.x + b.x; o.y += a.y + b.y; o.z += a.z + b.z; o.w += a.w + b.w;
  ((float4*)out)[i] = o;
}

extern "C" void kernel_launch(void* const* d_in, const int* in_sizes, int n_in,
                              void* d_out, int out_size, void* d_ws, size_t ws_size,
                              hipStream_t stream){
  const float* x   = (const float*)d_in[0];
  const float* Wr  = (const float*)d_in[1];
  const float* Wg  = (const float*)d_in[2];
  const float* Wu  = (const float*)d_in[3];
  const float* Wd  = (const float*)d_in[4];
  const float* Wsg = (const float*)d_in[5];
  const float* Wsu = (const float*)d_in[6];
  const float* Wsd = (const float*)d_in[7];
  float* out = (float*)d_out;
  (void)in_sizes; (void)n_in; (void)out_size; (void)ws_size;

  char* ws = (char*)d_ws;
  size_t off = 0;
  auto alloc = [&](size_t bytes)->char*{
    char* p = ws + off; off += (bytes + 255) & ~(size_t)255; return p;
  };
  // ~66 MB total workspace
  unsigned short* xb       = (unsigned short*)alloc((size_t)T_TOK * D_HID * 2);
  unsigned short* h_shared = (unsigned short*)alloc((size_t)T_TOK * FS_SH * 2);
  unsigned short* h_routed = (unsigned short*)alloc((size_t)T_TOK * 2 * F_EXP * 2);
  float*          y_routed = (float*)alloc((size_t)T_TOK * 2 * D_HID * 4);
  int*   topk_e       = (int*)alloc(T_TOK*2*sizeof(int));
  float* topk_w       = (float*)alloc(T_TOK*2*sizeof(float));
  int*   cnt          = (int*)alloc(E_NUM*sizeof(int));
  int*   offs         = (int*)alloc(E_NUM*sizeof(int));
  int*   assign_token = (int*)alloc(T_TOK*2*sizeof(int));
  float* assign_w     = (float*)alloc(T_TOK*2*sizeof(float));
  int*   token_slot   = (int*)alloc(T_TOK*2*sizeof(int));

  convert_x_kernel<<<(T_TOK*D_HID/4)/256, 256, 0, stream>>>(x, xb);
  router_kernel<<<T_TOK, 64, 0, stream>>>(x, Wr, topk_e, topk_w);
  build_lists_kernel<<<1, 64, 0, stream>>>(topk_e, topk_w, cnt, offs, assign_token, assign_w, token_slot);

  // shared expert gate+up:  [2048 x 2816] over K=2048
  gemm_gateup<0><<<dim3(FS_SH/128, T_TOK/128), 256, 0, stream>>>(
      xb, Wsg, Wsu, h_shared, nullptr, nullptr, nullptr, FS_SH, D_HID);
  // routed gate+up (gathered rows): [4096 x 1408] over K=2048
  gemm_gateup<1><<<dim3(F_EXP/128, E_NUM*16), 256, 0, stream>>>(
      xb, Wg, Wu, h_routed, cnt, offs, assign_token, F_EXP, D_HID);
  // shared down -> d_out: [2048 x 2048] over K=2816
  gemm_down<0><<<dim3(D_HID/128, T_TOK/128), 256, 0, stream>>>(
      h_shared, Wsd, out, nullptr, nullptr, nullptr, D_HID, FS_SH);
  // routed down -> weighted y_routed: [4096 x 2048] over K=1408
  gemm_down<1><<<dim3(D_HID/128, E_NUM*16), 256, 0, stream>>>(
      h_routed, Wd, y_routed, cnt, offs, assign_w, D_HID, F_EXP);

  combine_kernel<<<(T_TOK*D_HID/4)/256, 256, 0, stream>>>(out, y_routed, token_slot);
}

// Round 2
// 775.731 us; speedup vs baseline: 1.5895x; 1.5895x over previous
//
#include <hip/hip_runtime.h>
#include <hip/hip_bf16.h>

#define D_HID 2048
#define F_EXP 1408
#define E_NUM 8
#define FS_SH 2816
#define T_TOK 2048

typedef __attribute__((ext_vector_type(8))) short bf16x8;
typedef __attribute__((ext_vector_type(4))) float f32x4;
typedef __attribute__((ext_vector_type(4))) unsigned int u32x4;
typedef __attribute__((ext_vector_type(4))) unsigned short u16x4;

__device__ __forceinline__ unsigned short f2bf(float f){
  unsigned u = __float_as_uint(f);
  u += 0x7fffu + ((u >> 16) & 1u);          // RNE
  return (unsigned short)(u >> 16);
}

// ---------------- x fp32 -> bf16 ----------------
__global__ void convert_x_kernel(const float* __restrict__ x, unsigned short* __restrict__ xb){
  const int i = blockIdx.x * blockDim.x + threadIdx.x;   // one float4 per thread, exact grid
  float4 v = ((const float4*)x)[i];
  u16x4 h;
  h[0]=f2bf(v.x); h[1]=f2bf(v.y); h[2]=f2bf(v.z); h[3]=f2bf(v.w);
  ((u16x4*)xb)[i] = h;
}

// ---------------- router: logits, softmax, top-2 ----------------
__global__ __launch_bounds__(64) void router_kernel(const float* __restrict__ x,
                                                    const float* __restrict__ Wr,
                                                    int* __restrict__ topk_e,
                                                    float* __restrict__ topk_w){
  const int t = blockIdx.x;
  const int lane = threadIdx.x;
  const float* xt = x + (size_t)t * D_HID;
  float acc[E_NUM];
  #pragma unroll
  for (int e=0;e<E_NUM;e++) acc[e]=0.f;
  for (int d=lane; d<D_HID; d+=64){
    const float xv = xt[d];
    #pragma unroll
    for (int e=0;e<E_NUM;e++) acc[e] += xv * Wr[e*D_HID + d];
  }
  #pragma unroll
  for (int e=0;e<E_NUM;e++){
    #pragma unroll
    for (int off=32; off>0; off>>=1) acc[e] += __shfl_xor(acc[e], off);
  }
  if (lane==0){
    float m = acc[0];
    #pragma unroll
    for (int e=1;e<E_NUM;e++) m = fmaxf(m, acc[e]);
    float p[E_NUM]; float s = 0.f;
    #pragma unroll
    for (int e=0;e<E_NUM;e++){ p[e] = expf(acc[e]-m); s += p[e]; }
    const float inv = 1.f/s;
    int i0=0; float b0=p[0];
    #pragma unroll
    for (int e=1;e<E_NUM;e++) if (p[e] > b0){ b0=p[e]; i0=e; }
    int i1=-1; float b1=-1.f;
    #pragma unroll
    for (int e=0;e<E_NUM;e++) if (e!=i0 && p[e] > b1){ b1=p[e]; i1=e; }
    topk_e[t*2+0]=i0; topk_e[t*2+1]=i1;
    topk_w[t*2+0]=b0*inv; topk_w[t*2+1]=b1*inv;
  }
}

// ---------------- deterministic expert-grouped list build (parallel counting sort) ----
// 1 block x 1024 threads; entry i = (token i>>1, k = i&1); thread handles 4 consecutive
// entries. Stable placement identical to a serial scan of entries in order.
__global__ __launch_bounds__(1024) void build_lists_kernel(
    const int* __restrict__ topk_e, const float* __restrict__ topk_w,
    int* __restrict__ cnt, int* __restrict__ offs,
    int* __restrict__ assign_token, float* __restrict__ assign_w,
    int* __restrict__ token_slot)
{
  const int tid  = threadIdx.x;
  const int lane = tid & 63;
  const int wv   = tid >> 6;                 // 16 waves
  __shared__ int wsum[E_NUM][16];
  __shared__ int tot_s[E_NUM];
  __shared__ int offs_s[E_NUM];

  int   e_loc[4];
  float w_loc[4];
  #pragma unroll
  for (int j=0;j<4;j++){ e_loc[j]=topk_e[tid*4+j]; w_loc[j]=topk_w[tid*4+j]; }

  // per-thread counts (static-indexed)
  int c[E_NUM];
  #pragma unroll
  for (int e=0;e<E_NUM;e++){
    int s = 0;
    #pragma unroll
    for (int j=0;j<4;j++) s += (e_loc[j]==e) ? 1 : 0;
    c[e] = s;
  }
  // wave-level inclusive scan per expert -> lane-exclusive prefix + wave totals
  int pre[E_NUM];
  #pragma unroll
  for (int e=0;e<E_NUM;e++){
    int v = c[e];
    #pragma unroll
    for (int off=1; off<64; off<<=1){
      int t = __shfl_up(v, off);
      if (lane >= off) v += t;
    }
    if (lane==63) wsum[e][wv] = v;
    pre[e] = v - c[e];
  }
  __syncthreads();
  // threads 0..7: exclusive scan of the 16 wave sums for their expert
  if (tid < E_NUM){
    int s = 0;
    #pragma unroll
    for (int w=0; w<16; w++){ int t = wsum[tid][w]; wsum[tid][w] = s; s += t; }
    tot_s[tid] = s;
    cnt[tid]   = s;
  }
  __syncthreads();
  if (tid == 0){
    int s = 0;
    #pragma unroll
    for (int e=0;e<E_NUM;e++){ offs_s[e] = s; offs[e] = s; s += tot_s[e]; }
  }
  __syncthreads();
  // place entries
  int local[E_NUM];
  #pragma unroll
  for (int e=0;e<E_NUM;e++) local[e]=0;
  #pragma unroll
  for (int j=0;j<4;j++){
    const int e = e_loc[j];
    int pos = 0;
    #pragma unroll
    for (int ee=0; ee<E_NUM; ee++)
      if (e == ee) pos = offs_s[ee] + wsum[ee][wv] + pre[ee] + local[ee];
    #pragma unroll
    for (int ee=0; ee<E_NUM; ee++) local[ee] += (e == ee) ? 1 : 0;
    const int entry = tid*4 + j;
    assign_token[pos] = entry >> 1;
    assign_w[pos]     = w_loc[j];
    token_slot[entry] = pos;
  }
}

// ---------------- fused gate+up GEMM: H = silu(A Wg^T) * (A Wu^T) ----------------
// A: bf16 [*,K]; W*: fp32 [ (E,)N,K ]; Hout: bf16 [*,N].  BM=BN=128, BK=64, 256 thr / 4 waves.
template<int GATHER>
__global__ __launch_bounds__(256,1) void gemm_gateup(
    const unsigned short* __restrict__ A,
    const float* __restrict__ Wg_all,
    const float* __restrict__ Wu_all,
    unsigned short* __restrict__ Hout,
    const int* __restrict__ cnt, const int* __restrict__ offs,
    const int* __restrict__ assign_token,
    int N, int K)
{
  __shared__ __align__(16) char As[128*128];
  __shared__ __align__(16) char Bg[128*128];
  __shared__ __align__(16) char Bu[128*128];

  const int tid  = threadIdx.x;
  const int lane = tid & 63;
  const int wave = tid >> 6;
  const int wr = wave >> 1, wc = wave & 1;
  const int nt = blockIdx.x;

  int rowbase_out, valid, rowmax = 0;
  const float *Wgp, *Wup;
  if (GATHER){
    const int e  = blockIdx.y >> 4;
    const int mt = blockIdx.y & 15;
    const int c  = cnt[e];
    if (mt*128 >= c) return;
    const int o = offs[e];
    rowbase_out = o + mt*128;
    valid = c - mt*128; if (valid > 128) valid = 128;
    rowmax = o + c - 1;
    Wgp = Wg_all + (size_t)e * (size_t)N * (size_t)K;
    Wup = Wu_all + (size_t)e * (size_t)N * (size_t)K;
  } else {
    rowbase_out = blockIdx.y * 128;
    valid = 128;
    Wgp = Wg_all; Wup = Wu_all;
  }

  f32x4 accg[4][4], accu[4][4];
  const f32x4 z = {0.f,0.f,0.f,0.f};
  #pragma unroll
  for (int m=0;m<4;m++)
    #pragma unroll
    for (int n=0;n<4;n++){ accg[m][n]=z; accu[m][n]=z; }

  // A staging: pre-swizzled global source so linear global_load_lds dest + swizzled read agree
  const char* asrc[4];
  #pragma unroll
  for (int p=0;p<4;p++){
    const int c   = ((wave*4 + p) << 6) + lane;
    const int row = c >> 3;
    const int cb  = (c & 7) << 4;
    const int srccol = cb ^ ((row & 7) << 4);
    size_t grow;
    if (GATHER){
      int idx = rowbase_out + row;
      if (idx > rowmax) idx = rowmax;
      grow = (size_t)assign_token[idx];
    } else {
      grow = (size_t)(rowbase_out + row);
    }
    asrc[p] = (const char*)(A + grow * (size_t)K) + srccol;
  }
  const int brow = tid >> 1;
  const int hc   = (tid & 1) * 32;
  const int bswz = (brow & 7) << 4;
  const float* sg0 = Wgp + (size_t)(nt*128 + brow) * K + hc;
  const float* su0 = Wup + (size_t)(nt*128 + brow) * K + hc;

  const int nK = K >> 6;
  for (int kt = 0; kt < nK; ++kt){
    __syncthreads();
    #pragma unroll
    for (int p=0;p<4;p++){
      __builtin_amdgcn_global_load_lds(
        (const __attribute__((address_space(1))) void*)(asrc[p] + (size_t)kt*128),
        (__attribute__((address_space(3))) void*)(As + (wave*4 + p)*1024),
        16, 0, 0);
    }
    {
      const float* sg = sg0 + (size_t)kt*64;
      const float* su = su0 + (size_t)kt*64;
      unsigned short hg[32], hu[32];
      #pragma unroll
      for (int j=0;j<8;j++){
        float4 v = ((const float4*)sg)[j];
        hg[j*4+0]=f2bf(v.x); hg[j*4+1]=f2bf(v.y); hg[j*4+2]=f2bf(v.z); hg[j*4+3]=f2bf(v.w);
      }
      #pragma unroll
      for (int j=0;j<8;j++){
        float4 v = ((const float4*)su)[j];
        hu[j*4+0]=f2bf(v.x); hu[j*4+1]=f2bf(v.y); hu[j*4+2]=f2bf(v.z); hu[j*4+3]=f2bf(v.w);
      }
      #pragma unroll
      for (int cc=0; cc<4; cc++){
        const int colbyte = hc*2 + cc*16;
        const int dst = brow*128 + (colbyte ^ bswz);
        *(u32x4*)(Bg + dst) = *(const u32x4*)&hg[cc*8];
        *(u32x4*)(Bu + dst) = *(const u32x4*)&hu[cc*8];
      }
    }
    __syncthreads();
    #pragma unroll
    for (int kk=0;kk<2;kk++){
      const int kb = kk*64 + ((lane >> 4) << 4);
      bf16x8 a[4], bg[4], bu[4];
      #pragma unroll
      for (int m=0;m<4;m++){
        const int r = wr*64 + m*16 + (lane & 15);
        a[m] = *(const bf16x8*)(As + r*128 + (kb ^ ((r & 7) << 4)));
      }
      #pragma unroll
      for (int n=0;n<4;n++){
        const int r = wc*64 + n*16 + (lane & 15);
        const int ofs = r*128 + (kb ^ ((r & 7) << 4));
        bg[n] = *(const bf16x8*)(Bg + ofs);
        bu[n] = *(const bf16x8*)(Bu + ofs);
      }
      #pragma unroll
      for (int m=0;m<4;m++)
        #pragma unroll
        for (int n=0;n<4;n++){
          accg[m][n] = __builtin_amdgcn_mfma_f32_16x16x32_bf16(a[m], bg[n], accg[m][n], 0,0,0);
          accu[m][n] = __builtin_amdgcn_mfma_f32_16x16x32_bf16(a[m], bu[n], accu[m][n], 0,0,0);
        }
    }
  }
  const int colbase = nt*128 + wc*64;
  #pragma unroll
  for (int m=0;m<4;m++){
    #pragma unroll
    for (int r=0;r<4;r++){
      const int rr = wr*64 + m*16 + ((lane >> 4) << 2) + r;
      if (rr < valid){
        unsigned short* orow = Hout + (size_t)(rowbase_out + rr) * N;
        #pragma unroll
        for (int n=0;n<4;n++){
          const int col = colbase + n*16 + (lane & 15);
          const float g = accg[m][n][r];
          const float u = accu[m][n][r];
          const float h = (g / (1.f + __expf(-g))) * u;
          orow[col] = f2bf(h);
        }
      }
    }
  }
}

// ---------------- down GEMM: Out = (A Wd^T) [* row weight] ----------------
template<int ROUTED>
__global__ __launch_bounds__(256,1) void gemm_down(
    const unsigned short* __restrict__ A,   // bf16 [*,K]
    const float* __restrict__ Wd_all,       // fp32 [(E,)N,K]
    float* __restrict__ Out,                // fp32 [*,N]
    const int* __restrict__ cnt, const int* __restrict__ offs,
    const float* __restrict__ assign_w,
    int N, int K)
{
  __shared__ __align__(16) char As[128*128];
  __shared__ __align__(16) char Bs[128*128];

  const int tid  = threadIdx.x;
  const int lane = tid & 63;
  const int wave = tid >> 6;
  const int wr = wave >> 1, wc = wave & 1;
  const int nt = blockIdx.x;

  int rowbase_out, valid, rowmax = 0;
  const float *Wp;
  if (ROUTED){
    const int e  = blockIdx.y >> 4;
    const int mt = blockIdx.y & 15;
    const int c  = cnt[e];
    if (mt*128 >= c) return;
    const int o = offs[e];
    rowbase_out = o + mt*128;
    valid = c - mt*128; if (valid > 128) valid = 128;
    rowmax = o + c - 1;
    Wp = Wd_all + (size_t)e * (size_t)N * (size_t)K;
  } else {
    rowbase_out = blockIdx.y * 128;
    valid = 128;
    Wp = Wd_all;
  }

  f32x4 acc[4][4];
  const f32x4 z = {0.f,0.f,0.f,0.f};
  #pragma unroll
  for (int m=0;m<4;m++)
    #pragma unroll
    for (int n=0;n<4;n++) acc[m][n]=z;

  const char* asrc[4];
  #pragma unroll
  for (int p=0;p<4;p++){
    const int c   = ((wave*4 + p) << 6) + lane;
    const int row = c >> 3;
    const int cb  = (c & 7) << 4;
    const int srccol = cb ^ ((row & 7) << 4);
    int idx = rowbase_out + row;
    if (ROUTED && idx > rowmax) idx = rowmax;
    asrc[p] = (const char*)(A + (size_t)idx * (size_t)K) + srccol;
  }
  const int brow = tid >> 1;
  const int hc   = (tid & 1) * 32;
  const int bswz = (brow & 7) << 4;
  const float* sb0 = Wp + (size_t)(nt*128 + brow) * K + hc;

  const int nK = K >> 6;
  for (int kt = 0; kt < nK; ++kt){
    __syncthreads();
    #pragma unroll
    for (int p=0;p<4;p++){
      __builtin_amdgcn_global_load_lds(
        (const __attribute__((address_space(1))) void*)(asrc[p] + (size_t)kt*128),
        (__attribute__((address_space(3))) void*)(As + (wave*4 + p)*1024),
        16, 0, 0);
    }
    {
      const float* sb = sb0 + (size_t)kt*64;
      unsigned short hb[32];
      #pragma unroll
      for (int j=0;j<8;j++){
        float4 v = ((const float4*)sb)[j];
        hb[j*4+0]=f2bf(v.x); hb[j*4+1]=f2bf(v.y); hb[j*4+2]=f2bf(v.z); hb[j*4+3]=f2bf(v.w);
      }
      #pragma unroll
      for (int cc=0; cc<4; cc++){
        const int colbyte = hc*2 + cc*16;
        const int dst = brow*128 + (colbyte ^ bswz);
        *(u32x4*)(Bs + dst) = *(const u32x4*)&hb[cc*8];
      }
    }
    __syncthreads();
    #pragma unroll
    for (int kk=0;kk<2;kk++){
      const int kb = kk*64 + ((lane >> 4) << 4);
      bf16x8 a[4], b[4];
      #pragma unroll
      for (int m=0;m<4;m++){
        const int r = wr*64 + m*16 + (lane & 15);
        a[m] = *(const bf16x8*)(As + r*128 + (kb ^ ((r & 7) << 4)));
      }
      #pragma unroll
      for (int n=0;n<4;n++){
        const int r = wc*64 + n*16 + (lane & 15);
        b[n] = *(const bf16x8*)(Bs + r*128 + (kb ^ ((r & 7) << 4)));
      }
      #pragma unroll
      for (int m=0;m<4;m++)
        #pragma unroll
        for (int n=0;n<4;n++)
          acc[m][n] = __builtin_amdgcn_mfma_f32_16x16x32_bf16(a[m], b[n], acc[m][n], 0,0,0);
    }
  }
  const int colbase = nt*128 + wc*64;
  #pragma unroll
  for (int m=0;m<4;m++){
    #pragma unroll
    for (int r=0;r<4;r++){
      const int rr = wr*64 + m*16 + ((lane >> 4) << 2) + r;
      if (rr < valid){
        float w = 1.f;
        if (ROUTED) w = assign_w[rowbase_out + rr];
        float* orow = Out + (size_t)(rowbase_out + rr) * N;
        #pragma unroll
        for (int n=0;n<4;n++){
          const int col = colbase + n*16 + (lane & 15);
          orow[col] = acc[m][n][r] * w;
        }
      }
    }
  }
}

// ---------------- combine: out += y[slot0] + y[slot1] ----------------
__global__ void combine_kernel(float* __restrict__ out, const float* __restrict__ y,
                               const int* __restrict__ token_slot){
  const int i  = blockIdx.x * blockDim.x + threadIdx.x;   // float4 index
  const int t  = i >> 9;                                   // 512 float4 per row (D=2048)
  const int r4 = i & 511;
  const int s0 = token_slot[t*2+0];
  const int s1 = token_slot[t*2+1];
  const float4 a = ((const float4*)(y + (size_t)s0 * D_HID))[r4];
  const float4 b = ((const float4*)(y + (size_t)s1 * D_HID))[r4];
  float4 o = ((float4*)out)[i];
  o.x += a.x + b.x; o.y += a.y + b.y; o.z += a.z + b.z; o.w += a.w + b.w;
  ((float4*)out)[i] = o;
}

extern "C" void kernel_launch(void* const* d_in, const int* in_sizes, int n_in,
                              void* d_out, int out_size, void* d_ws, size_t ws_size,
                              hipStream_t stream){
  const float* x   = (const float*)d_in[0];
  const float* Wr  = (const float*)d_in[1];
  const float* Wg  = (const float*)d_in[2];
  const float* Wu  = (const float*)d_in[3];
  const float* Wd  = (const float*)d_in[4];
  const float* Wsg = (const float*)d_in[5];
  const float* Wsu = (const float*)d_in[6];
  const float* Wsd = (const float*)d_in[7];
  float* out = (float*)d_out;
  (void)in_sizes; (void)n_in; (void)out_size; (void)ws_size;

  char* ws = (char*)d_ws;
  size_t off = 0;
  auto alloc = [&](size_t bytes)->char*{
    char* p = ws + off; off += (bytes + 255) & ~(size_t)255; return p;
  };
  // ~66 MB total workspace
  unsigned short* xb       = (unsigned short*)alloc((size_t)T_TOK * D_HID * 2);
  unsigned short* h_shared = (unsigned short*)alloc((size_t)T_TOK * FS_SH * 2);
  unsigned short* h_routed = (unsigned short*)alloc((size_t)T_TOK * 2 * F_EXP * 2);
  float*          y_routed = (float*)alloc((size_t)T_TOK * 2 * D_HID * 4);
  int*   topk_e       = (int*)alloc(T_TOK*2*sizeof(int));
  float* topk_w       = (float*)alloc(T_TOK*2*sizeof(float));
  int*   cnt          = (int*)alloc(E_NUM*sizeof(int));
  int*   offs         = (int*)alloc(E_NUM*sizeof(int));
  int*   assign_token = (int*)alloc(T_TOK*2*sizeof(int));
  float* assign_w     = (float*)alloc(T_TOK*2*sizeof(float));
  int*   token_slot   = (int*)alloc(T_TOK*2*sizeof(int));

  convert_x_kernel<<<(T_TOK*D_HID/4)/256, 256, 0, stream>>>(x, xb);
  router_kernel<<<T_TOK, 64, 0, stream>>>(x, Wr, topk_e, topk_w);
  build_lists_kernel<<<1, 1024, 0, stream>>>(topk_e, topk_w, cnt, offs, assign_token, assign_w, token_slot);

  // shared expert gate+up:  [2048 x 2816] over K=2048
  gemm_gateup<0><<<dim3(FS_SH/128, T_TOK/128), 256, 0, stream>>>(
      xb, Wsg, Wsu, h_shared, nullptr, nullptr, nullptr, FS_SH, D_HID);
  // routed gate+up (gathered rows): [4096 x 1408] over K=2048
  gemm_gateup<1><<<dim3(F_EXP/128, E_NUM*16), 256, 0, stream>>>(
      xb, Wg, Wu, h_routed, cnt, offs, assign_token, F_EXP, D_HID);
  // shared down -> d_out: [2048 x 2048] over K=2816
  gemm_down<0><<<dim3(D_HID/128, T_TOK/128), 256, 0, stream>>>(
      h_shared, Wsd, out, nullptr, nullptr, nullptr, D_HID, FS_SH);
  // routed down -> weighted y_routed: [4096 x 2048] over K=1408
  gemm_down<1><<<dim3(D_HID/128, E_NUM*16), 256, 0, stream>>>(
      h_routed, Wd, y_routed, cnt, offs, assign_w, D_HID, F_EXP);

  combine_kernel<<<(T_TOK*D_HID/4)/256, 256, 0, stream>>>(out, y_routed, token_slot);
}

// Round 3
// 481.253 us; speedup vs baseline: 2.5622x; 1.6119x over previous
//
#include <hip/hip_runtime.h>
#include <hip/hip_bf16.h>

#define D_HID 2048
#define F_EXP 1408
#define E_NUM 8
#define FS_SH 2816
#define T_TOK 2048

// bf16 element offsets inside the converted-weight block wb
#define O_WSG 0
#define O_WSU 5767168
#define O_WG  11534336
#define O_WU  34603008
#define O_WSD 57671680
#define O_WD  63438848
#define W_TOT 86507520

typedef __attribute__((ext_vector_type(8))) short bf16x8;
typedef __attribute__((ext_vector_type(4))) float f32x4;
typedef __attribute__((ext_vector_type(4))) unsigned int u32x4;
typedef __attribute__((ext_vector_type(4))) unsigned short u16x4;

__device__ __forceinline__ unsigned short f2bf(float f){
  unsigned u = __float_as_uint(f);
  u += 0x7fffu + ((u >> 16) & 1u);          // RNE
  return (unsigned short)(u >> 16);
}

// ---------------- x fp32 -> bf16 ----------------
__global__ void convert_x_kernel(const float* __restrict__ x, unsigned short* __restrict__ xb){
  const int i = blockIdx.x * blockDim.x + threadIdx.x;
  float4 v = ((const float4*)x)[i];
  u16x4 h;
  h[0]=f2bf(v.x); h[1]=f2bf(v.y); h[2]=f2bf(v.z); h[3]=f2bf(v.w);
  ((u16x4*)xb)[i] = h;
}

// ---------------- all weights fp32 -> bf16 (contiguous wb) ----------------
__global__ __launch_bounds__(256) void convert_w_kernel(
    const float* __restrict__ Wsg, const float* __restrict__ Wsu,
    const float* __restrict__ Wg,  const float* __restrict__ Wu,
    const float* __restrict__ Wsd, const float* __restrict__ Wd,
    unsigned short* __restrict__ dst)
{
  const long e0 = ((long)blockIdx.x * 256 + threadIdx.x) * 8;
  const float* src; long lo;
  if      (e0 < (long)O_WSU){ src = Wsg; lo = e0 - O_WSG; }
  else if (e0 < (long)O_WG ){ src = Wsu; lo = e0 - O_WSU; }
  else if (e0 < (long)O_WU ){ src = Wg;  lo = e0 - O_WG;  }
  else if (e0 < (long)O_WSD){ src = Wu;  lo = e0 - O_WU;  }
  else if (e0 < (long)O_WD ){ src = Wsd; lo = e0 - O_WSD; }
  else                      { src = Wd;  lo = e0 - O_WD;  }
  const float4 a = ((const float4*)(src + lo))[0];
  const float4 b = ((const float4*)(src + lo))[1];
  u16x4 h0, h1;
  h0[0]=f2bf(a.x); h0[1]=f2bf(a.y); h0[2]=f2bf(a.z); h0[3]=f2bf(a.w);
  h1[0]=f2bf(b.x); h1[1]=f2bf(b.y); h1[2]=f2bf(b.z); h1[3]=f2bf(b.w);
  ((u16x4*)(dst + e0))[0] = h0;
  ((u16x4*)(dst + e0))[1] = h1;
}

// ---------------- router: logits, softmax, top-2 ----------------
__global__ __launch_bounds__(64) void router_kernel(const float* __restrict__ x,
                                                    const float* __restrict__ Wr,
                                                    int* __restrict__ topk_e,
                                                    float* __restrict__ topk_w){
  const int t = blockIdx.x;
  const int lane = threadIdx.x;
  const float* xt = x + (size_t)t * D_HID;
  float acc[E_NUM];
  #pragma unroll
  for (int e=0;e<E_NUM;e++) acc[e]=0.f;
  for (int d=lane; d<D_HID; d+=64){
    const float xv = xt[d];
    #pragma unroll
    for (int e=0;e<E_NUM;e++) acc[e] += xv * Wr[e*D_HID + d];
  }
  #pragma unroll
  for (int e=0;e<E_NUM;e++){
    #pragma unroll
    for (int off=32; off>0; off>>=1) acc[e] += __shfl_xor(acc[e], off);
  }
  if (lane==0){
    float m = acc[0];
    #pragma unroll
    for (int e=1;e<E_NUM;e++) m = fmaxf(m, acc[e]);
    float p[E_NUM]; float s = 0.f;
    #pragma unroll
    for (int e=0;e<E_NUM;e++){ p[e] = expf(acc[e]-m); s += p[e]; }
    const float inv = 1.f/s;
    int i0=0; float b0=p[0];
    #pragma unroll
    for (int e=1;e<E_NUM;e++) if (p[e] > b0){ b0=p[e]; i0=e; }
    int i1=-1; float b1=-1.f;
    #pragma unroll
    for (int e=0;e<E_NUM;e++) if (e!=i0 && p[e] > b1){ b1=p[e]; i1=e; }
    topk_e[t*2+0]=i0; topk_e[t*2+1]=i1;
    topk_w[t*2+0]=b0*inv; topk_w[t*2+1]=b1*inv;
  }
}

// ---------------- deterministic expert-grouped list build (parallel counting sort) ----
__global__ __launch_bounds__(1024) void build_lists_kernel(
    const int* __restrict__ topk_e, const float* __restrict__ topk_w,
    int* __restrict__ cnt, int* __restrict__ offs,
    int* __restrict__ assign_token, float* __restrict__ assign_w,
    int* __restrict__ token_slot)
{
  const int tid  = threadIdx.x;
  const int lane = tid & 63;
  const int wv   = tid >> 6;                 // 16 waves
  __shared__ int wsum[E_NUM][16];
  __shared__ int tot_s[E_NUM];
  __shared__ int offs_s[E_NUM];

  int   e_loc[4];
  float w_loc[4];
  #pragma unroll
  for (int j=0;j<4;j++){ e_loc[j]=topk_e[tid*4+j]; w_loc[j]=topk_w[tid*4+j]; }

  int c[E_NUM];
  #pragma unroll
  for (int e=0;e<E_NUM;e++){
    int s = 0;
    #pragma unroll
    for (int j=0;j<4;j++) s += (e_loc[j]==e) ? 1 : 0;
    c[e] = s;
  }
  int pre[E_NUM];
  #pragma unroll
  for (int e=0;e<E_NUM;e++){
    int v = c[e];
    #pragma unroll
    for (int off=1; off<64; off<<=1){
      int t = __shfl_up(v, off);
      if (lane >= off) v += t;
    }
    if (lane==63) wsum[e][wv] = v;
    pre[e] = v - c[e];
  }
  __syncthreads();
  if (tid < E_NUM){
    int s = 0;
    #pragma unroll
    for (int w=0; w<16; w++){ int t = wsum[tid][w]; wsum[tid][w] = s; s += t; }
    tot_s[tid] = s;
    cnt[tid]   = s;
  }
  __syncthreads();
  if (tid == 0){
    int s = 0;
    #pragma unroll
    for (int e=0;e<E_NUM;e++){ offs_s[e] = s; offs[e] = s; s += tot_s[e]; }
  }
  __syncthreads();
  int local[E_NUM];
  #pragma unroll
  for (int e=0;e<E_NUM;e++) local[e]=0;
  #pragma unroll
  for (int j=0;j<4;j++){
    const int e = e_loc[j];
    int pos = 0;
    #pragma unroll
    for (int ee=0; ee<E_NUM; ee++)
      if (e == ee) pos = offs_s[ee] + wsum[ee][wv] + pre[ee] + local[ee];
    #pragma unroll
    for (int ee=0; ee<E_NUM; ee++) local[ee] += (e == ee) ? 1 : 0;
    const int entry = tid*4 + j;
    assign_token[pos] = entry >> 1;
    assign_w[pos]     = w_loc[j];
    token_slot[entry] = pos;
  }
}

// ================= NEW PATH: all-bf16 fused GEMMs =================

// Fused gate+up GEMM for shared AND routed experts in one launch.
// Blocks 0..351: shared (16 mtiles x 22 ntiles). Blocks 352..1759: routed (8e x 16mt x 11nt).
__global__ __launch_bounds__(256,1) void gateup_fused(
    const unsigned short* __restrict__ xb,
    const unsigned short* __restrict__ wb,
    unsigned short* __restrict__ h_shared,
    unsigned short* __restrict__ h_routed,
    const int* __restrict__ cnt, const int* __restrict__ offs,
    const int* __restrict__ assign_token)
{
  __shared__ __align__(16) char As[128*128];
  __shared__ __align__(16) char Bg[128*128];
  __shared__ __align__(16) char Bu[128*128];

  const int tid  = threadIdx.x;
  const int lane = tid & 63;
  const int wave = tid >> 6;
  const int wr = wave >> 1, wc = wave & 1;
  const int b = blockIdx.x;

  int rowbase, valid, rowmax, N, nt, gather;
  const unsigned short *wg_base, *wu_base;
  unsigned short* H;
  if (b < 352){
    const int mtile = b / 22; nt = b % 22;
    rowbase = mtile*128; valid = 128; rowmax = T_TOK-1; gather = 0;
    wg_base = wb + O_WSG + (size_t)(nt*128) * D_HID;
    wu_base = wb + O_WSU + (size_t)(nt*128) * D_HID;
    H = h_shared; N = FS_SH;
  } else {
    const int rb = b - 352, e = rb / 176, rem = rb % 176, mtile = rem / 11;
    nt = rem % 11;
    const int c = cnt[e];
    if (mtile*128 >= c) return;
    const int o = offs[e];
    rowbase = o + mtile*128;
    valid = c - mtile*128; if (valid > 128) valid = 128;
    rowmax = o + c - 1; gather = 1;
    wg_base = wb + O_WG + ((size_t)e*F_EXP + nt*128) * D_HID;
    wu_base = wb + O_WU + ((size_t)e*F_EXP + nt*128) * D_HID;
    H = h_routed; N = F_EXP;
  }

  f32x4 accg[4][4], accu[4][4];
  const f32x4 z = {0.f,0.f,0.f,0.f};
  #pragma unroll
  for (int m=0;m<4;m++)
    #pragma unroll
    for (int n=0;n<4;n++){ accg[m][n]=z; accu[m][n]=z; }

  // A sources: 4 chunks/wave, pre-swizzled global column
  const char* asrc[4];
  #pragma unroll
  for (int p=0;p<4;p++){
    const int c   = ((wave*4 + p) << 6) + lane;
    const int row = c >> 3;
    const int cb  = (c & 7) << 4;
    const int srccol = cb ^ ((row & 7) << 4);
    int idx = rowbase + row;
    if (idx > rowmax) idx = rowmax;
    const size_t grow = gather ? (size_t)assign_token[idx] : (size_t)idx;
    asrc[p] = (const char*)(xb + grow * (size_t)D_HID) + srccol;
  }
  // B sources: single pointer + uniform p-stride (rows advance by 8 per p)
  const int srow = wave*32 + (lane >> 3);
  const int scol = ((lane & 7) << 4) ^ ((lane >> 3) << 4);
  const char* gsrc = (const char*)(wg_base + (size_t)srow * D_HID) + scol;
  const char* usrc = (const char*)(wu_base + (size_t)srow * D_HID) + scol;
  const int pstr = 8 * D_HID * 2;

  const int nK = D_HID / 64;
  for (int kt = 0; kt < nK; ++kt){
    __syncthreads();
    #pragma unroll
    for (int p=0;p<4;p++){
      const int ldsoff = (wave*4 + p) * 1024;
      __builtin_amdgcn_global_load_lds(
        (const __attribute__((address_space(1))) void*)(asrc[p] + kt*128),
        (__attribute__((address_space(3))) void*)(As + ldsoff), 16, 0, 0);
      __builtin_amdgcn_global_load_lds(
        (const __attribute__((address_space(1))) void*)(gsrc + p*pstr + kt*128),
        (__attribute__((address_space(3))) void*)(Bg + ldsoff), 16, 0, 0);
      __builtin_amdgcn_global_load_lds(
        (const __attribute__((address_space(1))) void*)(usrc + p*pstr + kt*128),
        (__attribute__((address_space(3))) void*)(Bu + ldsoff), 16, 0, 0);
    }
    __syncthreads();
    #pragma unroll
    for (int kk=0;kk<2;kk++){
      const int kb = kk*64 + ((lane >> 4) << 4);
      bf16x8 a[4], bg[4], bu[4];
      #pragma unroll
      for (int m=0;m<4;m++){
        const int r = wr*64 + m*16 + (lane & 15);
        a[m] = *(const bf16x8*)(As + r*128 + (kb ^ ((r & 7) << 4)));
      }
      #pragma unroll
      for (int n=0;n<4;n++){
        const int r = wc*64 + n*16 + (lane & 15);
        const int ofs = r*128 + (kb ^ ((r & 7) << 4));
        bg[n] = *(const bf16x8*)(Bg + ofs);
        bu[n] = *(const bf16x8*)(Bu + ofs);
      }
      #pragma unroll
      for (int m=0;m<4;m++)
        #pragma unroll
        for (int n=0;n<4;n++){
          accg[m][n] = __builtin_amdgcn_mfma_f32_16x16x32_bf16(a[m], bg[n], accg[m][n], 0,0,0);
          accu[m][n] = __builtin_amdgcn_mfma_f32_16x16x32_bf16(a[m], bu[n], accu[m][n], 0,0,0);
        }
    }
  }
  const int colbase = nt*128 + wc*64;
  #pragma unroll
  for (int m=0;m<4;m++){
    #pragma unroll
    for (int r=0;r<4;r++){
      const int rr = wr*64 + m*16 + ((lane >> 4) << 2) + r;
      if (rr < valid){
        unsigned short* orow = H + (size_t)(rowbase + rr) * N;
        #pragma unroll
        for (int n=0;n<4;n++){
          const int col = colbase + n*16 + (lane & 15);
          const float g = accg[m][n][r];
          const float u = accu[m][n][r];
          const float h = (g / (1.f + __expf(-g))) * u;
          orow[col] = f2bf(h);
        }
      }
    }
  }
}

// Fused down GEMM: blocks 0..255 shared (16mt x 16nt, K=2816) -> out;
// blocks 256..2303 routed (8e x 16mt x 16nt, K=1408) -> weighted y_routed.
__global__ __launch_bounds__(256,1) void down_fused(
    const unsigned short* __restrict__ h_shared,
    const unsigned short* __restrict__ h_routed,
    const unsigned short* __restrict__ wb,
    float* __restrict__ out, float* __restrict__ y_routed,
    const int* __restrict__ cnt, const int* __restrict__ offs,
    const float* __restrict__ assign_w)
{
  __shared__ __align__(16) char As[128*128];
  __shared__ __align__(16) char Bs[128*128];

  const int tid  = threadIdx.x;
  const int lane = tid & 63;
  const int wave = tid >> 6;
  const int wr = wave >> 1, wc = wave & 1;
  const int b = blockIdx.x;

  int rowbase, valid, rowmax, K, nt, weighted;
  const unsigned short *A, *w_base;
  float* Out;
  if (b < 256){
    const int mtile = b / 16; nt = b % 16;
    rowbase = mtile*128; valid = 128; rowmax = T_TOK-1; weighted = 0;
    A = h_shared; K = FS_SH;
    w_base = wb + O_WSD + (size_t)(nt*128) * FS_SH;
    Out = out;
  } else {
    const int rb = b - 256, e = rb / 256, rem = rb % 256, mtile = rem / 16;
    nt = rem % 16;
    const int c = cnt[e];
    if (mtile*128 >= c) return;
    const int o = offs[e];
    rowbase = o + mtile*128;
    valid = c - mtile*128; if (valid > 128) valid = 128;
    rowmax = o + c - 1; weighted = 1;
    A = h_routed; K = F_EXP;
    w_base = wb + O_WD + ((size_t)e*D_HID + nt*128) * F_EXP;
    Out = y_routed;
  }
  const size_t K2 = (size_t)K * 2;

  f32x4 acc[4][4];
  const f32x4 z = {0.f,0.f,0.f,0.f};
  #pragma unroll
  for (int m=0;m<4;m++)
    #pragma unroll
    for (int n=0;n<4;n++) acc[m][n]=z;

  const char* asrc[4];
  #pragma unroll
  for (int p=0;p<4;p++){
    const int c   = ((wave*4 + p) << 6) + lane;
    const int row = c >> 3;
    const int cb  = (c & 7) << 4;
    const int srccol = cb ^ ((row & 7) << 4);
    int idx = rowbase + row;
    if (idx > rowmax) idx = rowmax;
    asrc[p] = (const char*)A + (size_t)idx * K2 + srccol;
  }
  const int srow = wave*32 + (lane >> 3);
  const int scol = ((lane & 7) << 4) ^ ((lane >> 3) << 4);
  const char* bsrc = (const char*)w_base + (size_t)srow * K2 + scol;
  const size_t pstr = 8 * K2;

  const int nK = K / 64;
  for (int kt = 0; kt < nK; ++kt){
    __syncthreads();
    #pragma unroll
    for (int p=0;p<4;p++){
      const int ldsoff = (wave*4 + p) * 1024;
      __builtin_amdgcn_global_load_lds(
        (const __attribute__((address_space(1))) void*)(asrc[p] + kt*128),
        (__attribute__((address_space(3))) void*)(As + ldsoff), 16, 0, 0);
      __builtin_amdgcn_global_load_lds(
        (const __attribute__((address_space(1))) void*)(bsrc + p*pstr + kt*128),
        (__attribute__((address_space(3))) void*)(Bs + ldsoff), 16, 0, 0);
    }
    __syncthreads();
    #pragma unroll
    for (int kk=0;kk<2;kk++){
      const int kb = kk*64 + ((lane >> 4) << 4);
      bf16x8 a[4], bb[4];
      #pragma unroll
      for (int m=0;m<4;m++){
        const int r = wr*64 + m*16 + (lane & 15);
        a[m] = *(const bf16x8*)(As + r*128 + (kb ^ ((r & 7) << 4)));
      }
      #pragma unroll
      for (int n=0;n<4;n++){
        const int r = wc*64 + n*16 + (lane & 15);
        bb[n] = *(const bf16x8*)(Bs + r*128 + (kb ^ ((r & 7) << 4)));
      }
      #pragma unroll
      for (int m=0;m<4;m++)
        #pragma unroll
        for (int n=0;n<4;n++)
          acc[m][n] = __builtin_amdgcn_mfma_f32_16x16x32_bf16(a[m], bb[n], acc[m][n], 0,0,0);
    }
  }
  const int colbase = nt*128 + wc*64;
  #pragma unroll
  for (int m=0;m<4;m++){
    #pragma unroll
    for (int r=0;r<4;r++){
      const int rr = wr*64 + m*16 + ((lane >> 4) << 2) + r;
      if (rr < valid){
        float w = 1.f;
        if (weighted) w = assign_w[rowbase + rr];
        float* orow = Out + (size_t)(rowbase + rr) * D_HID;
        #pragma unroll
        for (int n=0;n<4;n++){
          const int col = colbase + n*16 + (lane & 15);
          orow[col] = acc[m][n][r] * w;
        }
      }
    }
  }
}

// ================= FALLBACK PATH (round-2 fly-convert kernels) =================
template<int GATHER>
__global__ __launch_bounds__(256,1) void gemm_gateup(
    const unsigned short* __restrict__ A,
    const float* __restrict__ Wg_all,
    const float* __restrict__ Wu_all,
    unsigned short* __restrict__ Hout,
    const int* __restrict__ cnt, const int* __restrict__ offs,
    const int* __restrict__ assign_token,
    int N, int K)
{
  __shared__ __align__(16) char As[128*128];
  __shared__ __align__(16) char Bg[128*128];
  __shared__ __align__(16) char Bu[128*128];

  const int tid  = threadIdx.x;
  const int lane = tid & 63;
  const int wave = tid >> 6;
  const int wr = wave >> 1, wc = wave & 1;
  const int nt = blockIdx.x;

  int rowbase_out, valid, rowmax = 0;
  const float *Wgp, *Wup;
  if (GATHER){
    const int e  = blockIdx.y >> 4;
    const int mt = blockIdx.y & 15;
    const int c  = cnt[e];
    if (mt*128 >= c) return;
    const int o = offs[e];
    rowbase_out = o + mt*128;
    valid = c - mt*128; if (valid > 128) valid = 128;
    rowmax = o + c - 1;
    Wgp = Wg_all + (size_t)e * (size_t)N * (size_t)K;
    Wup = Wu_all + (size_t)e * (size_t)N * (size_t)K;
  } else {
    rowbase_out = blockIdx.y * 128;
    valid = 128;
    Wgp = Wg_all; Wup = Wu_all;
  }

  f32x4 accg[4][4], accu[4][4];
  const f32x4 z = {0.f,0.f,0.f,0.f};
  #pragma unroll
  for (int m=0;m<4;m++)
    #pragma unroll
    for (int n=0;n<4;n++){ accg[m][n]=z; accu[m][n]=z; }

  const char* asrc[4];
  #pragma unroll
  for (int p=0;p<4;p++){
    const int c   = ((wave*4 + p) << 6) + lane;
    const int row = c >> 3;
    const int cb  = (c & 7) << 4;
    const int srccol = cb ^ ((row & 7) << 4);
    size_t grow;
    if (GATHER){
      int idx = rowbase_out + row;
      if (idx > rowmax) idx = rowmax;
      grow = (size_t)assign_token[idx];
    } else {
      grow = (size_t)(rowbase_out + row);
    }
    asrc[p] = (const char*)(A + grow * (size_t)K) + srccol;
  }
  const int brow = tid >> 1;
  const int hc   = (tid & 1) * 32;
  const int bswz = (brow & 7) << 4;
  const float* sg0 = Wgp + (size_t)(nt*128 + brow) * K + hc;
  const float* su0 = Wup + (size_t)(nt*128 + brow) * K + hc;

  const int nK = K >> 6;
  for (int kt = 0; kt < nK; ++kt){
    __syncthreads();
    #pragma unroll
    for (int p=0;p<4;p++){
      __builtin_amdgcn_global_load_lds(
        (const __attribute__((address_space(1))) void*)(asrc[p] + (size_t)kt*128),
        (__attribute__((address_space(3))) void*)(As + (wave*4 + p)*1024),
        16, 0, 0);
    }
    {
      const float* sg = sg0 + (size_t)kt*64;
      const float* su = su0 + (size_t)kt*64;
      unsigned short hg[32], hu[32];
      #pragma unroll
      for (int j=0;j<8;j++){
        float4 v = ((const float4*)sg)[j];
        hg[j*4+0]=f2bf(v.x); hg[j*4+1]=f2bf(v.y); hg[j*4+2]=f2bf(v.z); hg[j*4+3]=f2bf(v.w);
      }
      #pragma unroll
      for (int j=0;j<8;j++){
        float4 v = ((const float4*)su)[j];
        hu[j*4+0]=f2bf(v.x); hu[j*4+1]=f2bf(v.y); hu[j*4+2]=f2bf(v.z); hu[j*4+3]=f2bf(v.w);
      }
      #pragma unroll
      for (int cc=0; cc<4; cc++){
        const int colbyte = hc*2 + cc*16;
        const int dst = brow*128 + (colbyte ^ bswz);
        *(u32x4*)(Bg + dst) = *(const u32x4*)&hg[cc*8];
        *(u32x4*)(Bu + dst) = *(const u32x4*)&hu[cc*8];
      }
    }
    __syncthreads();
    #pragma unroll
    for (int kk=0;kk<2;kk++){
      const int kb = kk*64 + ((lane >> 4) << 4);
      bf16x8 a[4], bg[4], bu[4];
      #pragma unroll
      for (int m=0;m<4;m++){
        const int r = wr*64 + m*16 + (lane & 15);
        a[m] = *(const bf16x8*)(As + r*128 + (kb ^ ((r & 7) << 4)));
      }
      #pragma unroll
      for (int n=0;n<4;n++){
        const int r = wc*64 + n*16 + (lane & 15);
        const int ofs = r*128 + (kb ^ ((r & 7) << 4));
        bg[n] = *(const bf16x8*)(Bg + ofs);
        bu[n] = *(const bf16x8*)(Bu + ofs);
      }
      #pragma unroll
      for (int m=0;m<4;m++)
        #pragma unroll
        for (int n=0;n<4;n++){
          accg[m][n] = __builtin_amdgcn_mfma_f32_16x16x32_bf16(a[m], bg[n], accg[m][n], 0,0,0);
          accu[m][n] = __builtin_amdgcn_mfma_f32_16x16x32_bf16(a[m], bu[n], accu[m][n], 0,0,0);
        }
    }
  }
  const int colbase = nt*128 + wc*64;
  #pragma unroll
  for (int m=0;m<4;m++){
    #pragma unroll
    for (int r=0;r<4;r++){
      const int rr = wr*64 + m*16 + ((lane >> 4) << 2) + r;
      if (rr < valid){
        unsigned short* orow = Hout + (size_t)(rowbase_out + rr) * N;
        #pragma unroll
        for (int n=0;n<4;n++){
          const int col = colbase + n*16 + (lane & 15);
          const float g = accg[m][n][r];
          const float u = accu[m][n][r];
          const float h = (g / (1.f + __expf(-g))) * u;
          orow[col] = f2bf(h);
        }
      }
    }
  }
}

template<int ROUTED>
__global__ __launch_bounds__(256,1) void gemm_down(
    const unsigned short* __restrict__ A,
    const float* __restrict__ Wd_all,
    float* __restrict__ Out,
    const int* __restrict__ cnt, const int* __restrict__ offs,
    const float* __restrict__ assign_w,
    int N, int K)
{
  __shared__ __align__(16) char As[128*128];
  __shared__ __align__(16) char Bs[128*128];

  const int tid  = threadIdx.x;
  const int lane = tid & 63;
  const int wave = tid >> 6;
  const int wr = wave >> 1, wc = wave & 1;
  const int nt = blockIdx.x;

  int rowbase_out, valid, rowmax = 0;
  const float *Wp;
  if (ROUTED){
    const int e  = blockIdx.y >> 4;
    const int mt = blockIdx.y & 15;
    const int c  = cnt[e];
    if (mt*128 >= c) return;
    const int o = offs[e];
    rowbase_out = o + mt*128;
    valid = c - mt*128; if (valid > 128) valid = 128;
    rowmax = o + c - 1;
    Wp = Wd_all + (size_t)e * (size_t)N * (size_t)K;
  } else {
    rowbase_out = blockIdx.y * 128;
    valid = 128;
    Wp = Wd_all;
  }

  f32x4 acc[4][4];
  const f32x4 z = {0.f,0.f,0.f,0.f};
  #pragma unroll
  for (int m=0;m<4;m++)
    #pragma unroll
    for (int n=0;n<4;n++) acc[m][n]=z;

  const char* asrc[4];
  #pragma unroll
  for (int p=0;p<4;p++){
    const int c   = ((wave*4 + p) << 6) + lane;
    const int row = c >> 3;
    const int cb  = (c & 7) << 4;
    const int srccol = cb ^ ((row & 7) << 4);
    int idx = rowbase_out + row;
    if (ROUTED && idx > rowmax) idx = rowmax;
    asrc[p] = (const char*)(A + (size_t)idx * (size_t)K) + srccol;
  }
  const int brow = tid >> 1;
  const int hc   = (tid & 1) * 32;
  const int bswz = (brow & 7) << 4;
  const float* sb0 = Wp + (size_t)(nt*128 + brow) * K + hc;

  const int nK = K >> 6;
  for (int kt = 0; kt < nK; ++kt){
    __syncthreads();
    #pragma unroll
    for (int p=0;p<4;p++){
      __builtin_amdgcn_global_load_lds(
        (const __attribute__((address_space(1))) void*)(asrc[p] + (size_t)kt*128),
        (__attribute__((address_space(3))) void*)(As + (wave*4 + p)*1024),
        16, 0, 0);
    }
    {
      const float* sb = sb0 + (size_t)kt*64;
      unsigned short hb[32];
      #pragma unroll
      for (int j=0;j<8;j++){
        float4 v = ((const float4*)sb)[j];
        hb[j*4+0]=f2bf(v.x); hb[j*4+1]=f2bf(v.y); hb[j*4+2]=f2bf(v.z); hb[j*4+3]=f2bf(v.w);
      }
      #pragma unroll
      for (int cc=0; cc<4; cc++){
        const int colbyte = hc*2 + cc*16;
        const int dst = brow*128 + (colbyte ^ bswz);
        *(u32x4*)(Bs + dst) = *(const u32x4*)&hb[cc*8];
      }
    }
    __syncthreads();
    #pragma unroll
    for (int kk=0;kk<2;kk++){
      const int kb = kk*64 + ((lane >> 4) << 4);
      bf16x8 a[4], b[4];
      #pragma unroll
      for (int m=0;m<4;m++){
        const int r = wr*64 + m*16 + (lane & 15);
        a[m] = *(const bf16x8*)(As + r*128 + (kb ^ ((r & 7) << 4)));
      }
      #pragma unroll
      for (int n=0;n<4;n++){
        const int r = wc*64 + n*16 + (lane & 15);
        b[n] = *(const bf16x8*)(Bs + r*128 + (kb ^ ((r & 7) << 4)));
      }
      #pragma unroll
      for (int m=0;m<4;m++)
        #pragma unroll
        for (int n=0;n<4;n++)
          acc[m][n] = __builtin_amdgcn_mfma_f32_16x16x32_bf16(a[m], b[n], acc[m][n], 0,0,0);
    }
  }
  const int colbase = nt*128 + wc*64;
  #pragma unroll
  for (int m=0;m<4;m++){
    #pragma unroll
    for (int r=0;r<4;r++){
      const int rr = wr*64 + m*16 + ((lane >> 4) << 2) + r;
      if (rr < valid){
        float w = 1.f;
        if (ROUTED) w = assign_w[rowbase_out + rr];
        float* orow = Out + (size_t)(rowbase_out + rr) * N;
        #pragma unroll
        for (int n=0;n<4;n++){
          const int col = colbase + n*16 + (lane & 15);
          orow[col] = acc[m][n][r] * w;
        }
      }
    }
  }
}

// ---------------- combine: out += y[slot0] + y[slot1] ----------------
__global__ void combine_kernel(float* __restrict__ out, const float* __restrict__ y,
                               const int* __restrict__ token_slot){
  const int i  = blockIdx.x * blockDim.x + threadIdx.x;
  const int t  = i >> 9;
  const int r4 = i & 511;
  const int s0 = token_slot[t*2+0];
  const int s1 = token_slot[t*2+1];
  const float4 a = ((const float4*)(y + (size_t)s0 * D_HID))[r4];
  const float4 b = ((const float4*)(y + (size_t)s1 * D_HID))[r4];
  float4 o = ((float4*)out)[i];
  o.x += a.x + b.x; o.y += a.y + b.y; o.z += a.z + b.z; o.w += a.w + b.w;
  ((float4*)out)[i] = o;
}

extern "C" void kernel_launch(void* const* d_in, const int* in_sizes, int n_in,
                              void* d_out, int out_size, void* d_ws, size_t ws_size,
                              hipStream_t stream){
  const float* x   = (const float*)d_in[0];
  const float* Wr  = (const float*)d_in[1];
  const float* Wg  = (const float*)d_in[2];
  const float* Wu  = (const float*)d_in[3];
  const float* Wd  = (const float*)d_in[4];
  const float* Wsg = (const float*)d_in[5];
  const float* Wsu = (const float*)d_in[6];
  const float* Wsd = (const float*)d_in[7];
  float* out = (float*)d_out;
  (void)in_sizes; (void)n_in; (void)out_size;

  char* ws = (char*)d_ws;
  size_t off = 0;
  auto alloc = [&](size_t bytes)->char*{
    char* p = ws + off; off += (bytes + 255) & ~(size_t)255; return p;
  };

  const size_t need_new = (size_t)W_TOT*2 + (size_t)T_TOK*D_HID*2 + (size_t)T_TOK*FS_SH*2
                        + (size_t)T_TOK*2*F_EXP*2 + (size_t)T_TOK*2*D_HID*4 + (size_t)(7*16384 + 4096);
  const bool use_new = (ws_size >= need_new);

  unsigned short* wb = nullptr;
  if (use_new) wb = (unsigned short*)alloc((size_t)W_TOT * 2);
  unsigned short* xb       = (unsigned short*)alloc((size_t)T_TOK * D_HID * 2);
  unsigned short* h_shared = (unsigned short*)alloc((size_t)T_TOK * FS_SH * 2);
  unsigned short* h_routed = (unsigned short*)alloc((size_t)T_TOK * 2 * F_EXP * 2);
  float*          y_routed = (float*)alloc((size_t)T_TOK * 2 * D_HID * 4);
  int*   topk_e       = (int*)alloc(T_TOK*2*sizeof(int));
  float* topk_w       = (float*)alloc(T_TOK*2*sizeof(float));
  int*   cnt          = (int*)alloc(E_NUM*sizeof(int));
  int*   offs         = (int*)alloc(E_NUM*sizeof(int));
  int*   assign_token = (int*)alloc(T_TOK*2*sizeof(int));
  float* assign_w     = (float*)alloc(T_TOK*2*sizeof(float));
  int*   token_slot   = (int*)alloc(T_TOK*2*sizeof(int));

  convert_x_kernel<<<(T_TOK*D_HID/4)/256, 256, 0, stream>>>(x, xb);
  router_kernel<<<T_TOK, 64, 0, stream>>>(x, Wr, topk_e, topk_w);
  build_lists_kernel<<<1, 1024, 0, stream>>>(topk_e, topk_w, cnt, offs, assign_token, assign_w, token_slot);

  if (use_new){
    convert_w_kernel<<<W_TOT/8/256, 256, 0, stream>>>(Wsg, Wsu, Wg, Wu, Wsd, Wd, wb);
    gateup_fused<<<352 + E_NUM*16*11, 256, 0, stream>>>(
        xb, wb, h_shared, h_routed, cnt, offs, assign_token);
    down_fused<<<256 + E_NUM*16*16, 256, 0, stream>>>(
        h_shared, h_routed, wb, out, y_routed, cnt, offs, assign_w);
  } else {
    gemm_gateup<0><<<dim3(FS_SH/128, T_TOK/128), 256, 0, stream>>>(
        xb, Wsg, Wsu, h_shared, nullptr, nullptr, nullptr, FS_SH, D_HID);
    gemm_gateup<1><<<dim3(F_EXP/128, E_NUM*16), 256, 0, stream>>>(
        xb, Wg, Wu, h_routed, cnt, offs, assign_token, F_EXP, D_HID);
    gemm_down<0><<<dim3(D_HID/128, T_TOK/128), 256, 0, stream>>>(
        h_shared, Wsd, out, nullptr, nullptr, nullptr, D_HID, FS_SH);
    gemm_down<1><<<dim3(D_HID/128, E_NUM*16), 256, 0, stream>>>(
        h_routed, Wd, y_routed, cnt, offs, assign_w, D_HID, F_EXP);
  }

  combine_kernel<<<(T_TOK*D_HID/4)/256, 256, 0, stream>>>(out, y_routed, token_slot);
}

// Round 4
// 413.311 us; speedup vs baseline: 2.9834x; 1.1644x over previous
//
#include <hip/hip_runtime.h>
#include <hip/hip_bf16.h>

#define D_HID 2048
#define F_EXP 1408
#define E_NUM 8
#define FS_SH 2816
#define T_TOK 2048

// bf16 element offsets inside the converted-weight block wb
#define O_WSG 0
#define O_WSU 5767168
#define O_WG  11534336
#define O_WU  34603008
#define O_WSD 57671680
#define O_WD  63438848
#define W_TOT 86507520

#define MAXT 24          // max routed 256-row tiles (sum ceil(cnt_e/256) <= 23)
#define GU_SH_BLK 176    // shared gateup: 22 ntiles * 8 mtiles
#define DN_SH_BLK 128    // shared down:   16 ntiles * 8 mtiles

typedef __attribute__((ext_vector_type(8))) short bf16x8;
typedef __attribute__((ext_vector_type(4))) float f32x4;
typedef __attribute__((ext_vector_type(4))) unsigned short u16x4;

#define AS1 __attribute__((address_space(1)))
#define AS3 __attribute__((address_space(3)))

__device__ __forceinline__ unsigned short f2bf(float f){
  unsigned u = __float_as_uint(f);
  u += 0x7fffu + ((u >> 16) & 1u);          // RNE
  return (unsigned short)(u >> 16);
}

// ---------------- x fp32 -> bf16 ----------------
__global__ void convert_x_kernel(const float* __restrict__ x, unsigned short* __restrict__ xb){
  const int i = blockIdx.x * blockDim.x + threadIdx.x;
  float4 v = ((const float4*)x)[i];
  u16x4 h;
  h[0]=f2bf(v.x); h[1]=f2bf(v.y); h[2]=f2bf(v.z); h[3]=f2bf(v.w);
  ((u16x4*)xb)[i] = h;
}

// ---------------- all weights fp32 -> bf16 (contiguous wb) ----------------
__global__ __launch_bounds__(256) void convert_w_kernel(
    const float* __restrict__ Wsg, const float* __restrict__ Wsu,
    const float* __restrict__ Wg,  const float* __restrict__ Wu,
    const float* __restrict__ Wsd, const float* __restrict__ Wd,
    unsigned short* __restrict__ dst)
{
  const long e0 = ((long)blockIdx.x * 256 + threadIdx.x) * 8;
  const float* src; long lo;
  if      (e0 < (long)O_WSU){ src = Wsg; lo = e0 - O_WSG; }
  else if (e0 < (long)O_WG ){ src = Wsu; lo = e0 - O_WSU; }
  else if (e0 < (long)O_WU ){ src = Wg;  lo = e0 - O_WG;  }
  else if (e0 < (long)O_WSD){ src = Wu;  lo = e0 - O_WU;  }
  else if (e0 < (long)O_WD ){ src = Wsd; lo = e0 - O_WSD; }
  else                      { src = Wd;  lo = e0 - O_WD;  }
  const float4 a = ((const float4*)(src + lo))[0];
  const float4 b = ((const float4*)(src + lo))[1];
  u16x4 h0, h1;
  h0[0]=f2bf(a.x); h0[1]=f2bf(a.y); h0[2]=f2bf(a.z); h0[3]=f2bf(a.w);
  h1[0]=f2bf(b.x); h1[1]=f2bf(b.y); h1[2]=f2bf(b.z); h1[3]=f2bf(b.w);
  ((u16x4*)(dst + e0))[0] = h0;
  ((u16x4*)(dst + e0))[1] = h1;
}

// ---------------- router: logits, softmax, top-2 ----------------
__global__ __launch_bounds__(64) void router_kernel(const float* __restrict__ x,
                                                    const float* __restrict__ Wr,
                                                    int* __restrict__ topk_e,
                                                    float* __restrict__ topk_w){
  const int t = blockIdx.x;
  const int lane = threadIdx.x;
  const float* xt = x + (size_t)t * D_HID;
  float acc[E_NUM];
  #pragma unroll
  for (int e=0;e<E_NUM;e++) acc[e]=0.f;
  for (int d=lane; d<D_HID; d+=64){
    const float xv = xt[d];
    #pragma unroll
    for (int e=0;e<E_NUM;e++) acc[e] += xv * Wr[e*D_HID + d];
  }
  #pragma unroll
  for (int e=0;e<E_NUM;e++){
    #pragma unroll
    for (int off=32; off>0; off>>=1) acc[e] += __shfl_xor(acc[e], off);
  }
  if (lane==0){
    float m = acc[0];
    #pragma unroll
    for (int e=1;e<E_NUM;e++) m = fmaxf(m, acc[e]);
    float p[E_NUM]; float s = 0.f;
    #pragma unroll
    for (int e=0;e<E_NUM;e++){ p[e] = expf(acc[e]-m); s += p[e]; }
    const float inv = 1.f/s;
    int i0=0; float b0=p[0];
    #pragma unroll
    for (int e=1;e<E_NUM;e++) if (p[e] > b0){ b0=p[e]; i0=e; }
    int i1=-1; float b1=-1.f;
    #pragma unroll
    for (int e=0;e<E_NUM;e++) if (e!=i0 && p[e] > b1){ b1=p[e]; i1=e; }
    topk_e[t*2+0]=i0; topk_e[t*2+1]=i1;
    topk_w[t*2+0]=b0*inv; topk_w[t*2+1]=b1*inv;
  }
}

// ---------------- deterministic expert-grouped list build + tile records ----------------
__global__ __launch_bounds__(1024) void build_lists_kernel(
    const int* __restrict__ topk_e, const float* __restrict__ topk_w,
    int* __restrict__ cnt, int* __restrict__ offs,
    int* __restrict__ assign_token, float* __restrict__ assign_w,
    int* __restrict__ token_slot,
    int* __restrict__ tile_rowbase, int* __restrict__ tile_e,
    int* __restrict__ tile_valid, int* __restrict__ n_rt)
{
  const int tid  = threadIdx.x;
  const int lane = tid & 63;
  const int wv   = tid >> 6;                 // 16 waves
  __shared__ int wsum[E_NUM][16];
  __shared__ int tot_s[E_NUM];
  __shared__ int offs_s[E_NUM];

  int   e_loc[4];
  float w_loc[4];
  #pragma unroll
  for (int j=0;j<4;j++){ e_loc[j]=topk_e[tid*4+j]; w_loc[j]=topk_w[tid*4+j]; }

  int c[E_NUM];
  #pragma unroll
  for (int e=0;e<E_NUM;e++){
    int s = 0;
    #pragma unroll
    for (int j=0;j<4;j++) s += (e_loc[j]==e) ? 1 : 0;
    c[e] = s;
  }
  int pre[E_NUM];
  #pragma unroll
  for (int e=0;e<E_NUM;e++){
    int v = c[e];
    #pragma unroll
    for (int off=1; off<64; off<<=1){
      int t = __shfl_up(v, off);
      if (lane >= off) v += t;
    }
    if (lane==63) wsum[e][wv] = v;
    pre[e] = v - c[e];
  }
  __syncthreads();
  if (tid < E_NUM){
    int s = 0;
    #pragma unroll
    for (int w=0; w<16; w++){ int t = wsum[tid][w]; wsum[tid][w] = s; s += t; }
    tot_s[tid] = s;
    cnt[tid]   = s;
  }
  __syncthreads();
  if (tid == 0){
    int s = 0;
    #pragma unroll
    for (int e=0;e<E_NUM;e++){ offs_s[e] = s; offs[e] = s; s += tot_s[e]; }
    // compacted 256-row tile records for routed GEMMs
    int ntl = 0;
    for (int e=0;e<E_NUM;e++){
      for (int r=0; r<tot_s[e]; r+=256){
        tile_rowbase[ntl] = offs_s[e] + r;
        tile_e[ntl]       = e;
        int v = tot_s[e] - r; if (v > 256) v = 256;
        tile_valid[ntl]   = v;
        ntl++;
      }
    }
    n_rt[0] = ntl;
    for (int i=ntl;i<MAXT;i++){ tile_rowbase[i]=0; tile_e[i]=0; tile_valid[i]=0; }
  }
  __syncthreads();
  int local[E_NUM];
  #pragma unroll
  for (int e=0;e<E_NUM;e++) local[e]=0;
  #pragma unroll
  for (int j=0;j<4;j++){
    const int e = e_loc[j];
    int pos = 0;
    #pragma unroll
    for (int ee=0; ee<E_NUM; ee++)
      if (e == ee) pos = offs_s[ee] + wsum[ee][wv] + pre[ee] + local[ee];
    #pragma unroll
    for (int ee=0; ee<E_NUM; ee++) local[ee] += (e == ee) ? 1 : 0;
    const int entry = tid*4 + j;
    assign_token[pos] = entry >> 1;
    assign_w[pos]     = w_loc[j];
    token_slot[entry] = pos;
  }
}

// ================= fused gate+up GEMM, 2-phase double-buffered =================
// 512 thr / 8 waves (4M x 2N), BM=256, BN=128, BK=64. LDS = 128 KB.
// Blocks [0,176): shared (nt-major). Blocks [176,440): routed, tile = rb%24, nt = rb/24.
__global__ __launch_bounds__(512,1) void gateup_fused(
    const unsigned short* __restrict__ xb,
    const unsigned short* __restrict__ wb,
    unsigned short* __restrict__ h_shared,
    unsigned short* __restrict__ h_routed,
    const int* __restrict__ tile_rowbase, const int* __restrict__ tile_e,
    const int* __restrict__ tile_valid, const int* __restrict__ n_rt,
    const int* __restrict__ assign_token)
{
  __shared__ __align__(16) char As[2][256*128];   // 64 KB
  __shared__ __align__(16) char Bg[2][128*128];   // 32 KB
  __shared__ __align__(16) char Bu[2][128*128];   // 32 KB

  const int tid  = threadIdx.x;
  const int lane = tid & 63;
  const int wave = tid >> 6;       // 0..7
  const int wr = wave >> 1;        // 0..3
  const int wc = wave & 1;         // 0..1
  const int b = blockIdx.x;

  int nt, rowbase, valid, gather;
  const unsigned short *wg_base, *wu_base;
  unsigned short* H; int N;
  if (b < GU_SH_BLK){
    nt = b >> 3; const int mtile = b & 7;       // 8 consecutive blocks share a weight panel
    rowbase = mtile*256; valid = 256; gather = 0;
    wg_base = wb + O_WSG + (size_t)(nt*128) * D_HID;
    wu_base = wb + O_WSU + (size_t)(nt*128) * D_HID;
    H = h_shared; N = FS_SH;
  } else {
    const int rb = b - GU_SH_BLK;
    const int tile = rb % MAXT;
    nt = rb / MAXT;                              // 0..10
    if (tile >= n_rt[0]) return;
    rowbase = tile_rowbase[tile];
    valid   = tile_valid[tile];
    const int e = tile_e[tile];
    gather = 1;
    wg_base = wb + O_WG + ((size_t)e*F_EXP + nt*128) * D_HID;
    wu_base = wb + O_WU + ((size_t)e*F_EXP + nt*128) * D_HID;
    H = h_routed; N = F_EXP;
  }

  f32x4 accg[4][4], accu[4][4];
  const f32x4 z = {0.f,0.f,0.f,0.f};
  #pragma unroll
  for (int m=0;m<4;m++)
    #pragma unroll
    for (int n=0;n<4;n++){ accg[m][n]=z; accu[m][n]=z; }

  // A sources: 4 chunks/wave (1 KB each), pre-swizzled source column
  const char* asrc[4];
  const int rowmax = rowbase + valid - 1;
  const int srccol = ((lane&7)<<4) ^ ((lane>>3)<<4);
  #pragma unroll
  for (int p=0;p<4;p++){
    const int row = wave*32 + p*8 + (lane>>3);
    int idx = rowbase + row;
    if (idx > rowmax) idx = rowmax;
    const size_t grow = gather ? (size_t)assign_token[idx] : (size_t)idx;
    asrc[p] = (const char*)(xb + grow * (size_t)D_HID) + srccol;
  }
  // B sources: 2 chunks/wave each
  const int brow0 = wave*16 + (lane>>3);
  const char* gsrc = (const char*)(wg_base + (size_t)brow0 * D_HID) + srccol;
  const char* usrc = (const char*)(wu_base + (size_t)brow0 * D_HID) + srccol;
  const int pstrB = 8 * D_HID * 2;

  auto stage = [&](int bi, int kt){
    #pragma unroll
    for (int p=0;p<4;p++){
      __builtin_amdgcn_global_load_lds(
        (const AS1 void*)(asrc[p] + kt*128),
        (AS3 void*)(&As[bi][(wave*4 + p)*1024]), 16, 0, 0);
    }
    #pragma unroll
    for (int p=0;p<2;p++){
      __builtin_amdgcn_global_load_lds(
        (const AS1 void*)(gsrc + p*pstrB + kt*128),
        (AS3 void*)(&Bg[bi][(wave*2 + p)*1024]), 16, 0, 0);
      __builtin_amdgcn_global_load_lds(
        (const AS1 void*)(usrc + p*pstrB + kt*128),
        (AS3 void*)(&Bu[bi][(wave*2 + p)*1024]), 16, 0, 0);
    }
  };

  const int nK = D_HID / 64;   // 32
  stage(0, 0);
  __syncthreads();             // drains prologue loads
  int cur = 0;
  for (int kt = 0; kt < nK; ++kt){
    if (kt + 1 < nK) stage(cur^1, kt+1);   // prefetch next tile, overlaps compute below
    #pragma unroll
    for (int kk=0;kk<2;kk++){
      const int kb = kk*64 + ((lane >> 4) << 4);
      bf16x8 a[4], bg[4], bu[4];
      #pragma unroll
      for (int m=0;m<4;m++){
        const int r = wr*64 + m*16 + (lane & 15);
        a[m] = *(const bf16x8*)(&As[cur][r*128 + (kb ^ ((r & 7) << 4))]);
      }
      #pragma unroll
      for (int n=0;n<4;n++){
        const int r = wc*64 + n*16 + (lane & 15);
        const int ofs = r*128 + (kb ^ ((r & 7) << 4));
        bg[n] = *(const bf16x8*)(&Bg[cur][ofs]);
        bu[n] = *(const bf16x8*)(&Bu[cur][ofs]);
      }
      #pragma unroll
      for (int m=0;m<4;m++)
        #pragma unroll
        for (int n=0;n<4;n++){
          accg[m][n] = __builtin_amdgcn_mfma_f32_16x16x32_bf16(a[m], bg[n], accg[m][n], 0,0,0);
          accu[m][n] = __builtin_amdgcn_mfma_f32_16x16x32_bf16(a[m], bu[n], accu[m][n], 0,0,0);
        }
    }
    __syncthreads();           // vmcnt(0)+lgkmcnt(0)+barrier: prefetch landed, reads done
    cur ^= 1;
  }

  const int colbase = nt*128 + wc*64;
  #pragma unroll
  for (int m=0;m<4;m++){
    #pragma unroll
    for (int r=0;r<4;r++){
      const int rr = wr*64 + m*16 + ((lane >> 4) << 2) + r;
      if (rr < valid){
        unsigned short* orow = H + (size_t)(rowbase + rr) * N;
        #pragma unroll
        for (int n=0;n<4;n++){
          const int col = colbase + n*16 + (lane & 15);
          const float g = accg[m][n][r];
          const float u = accu[m][n][r];
          const float h = (g / (1.f + __expf(-g))) * u;
          orow[col] = f2bf(h);
        }
      }
    }
  }
}

// ================= fused down GEMM, 2-phase double-buffered =================
// Blocks [0,128): shared (K=2816) -> out. Blocks [128,512): routed (K=1408) -> weighted y_routed.
__global__ __launch_bounds__(512,1) void down_fused(
    const unsigned short* __restrict__ h_shared,
    const unsigned short* __restrict__ h_routed,
    const unsigned short* __restrict__ wb,
    float* __restrict__ out, float* __restrict__ y_routed,
    const int* __restrict__ tile_rowbase, const int* __restrict__ tile_e,
    const int* __restrict__ tile_valid, const int* __restrict__ n_rt,
    const float* __restrict__ assign_w)
{
  __shared__ __align__(16) char As[2][256*128];   // 64 KB
  __shared__ __align__(16) char Bs[2][128*128];   // 32 KB

  const int tid  = threadIdx.x;
  const int lane = tid & 63;
  const int wave = tid >> 6;
  const int wr = wave >> 1, wc = wave & 1;
  const int b = blockIdx.x;

  int nt, rowbase, valid, weighted, K;
  const unsigned short *A, *w_base;
  float* Out;
  if (b < DN_SH_BLK){
    nt = b >> 3; const int mtile = b & 7;
    rowbase = mtile*256; valid = 256; weighted = 0;
    A = h_shared; K = FS_SH;
    w_base = wb + O_WSD + (size_t)(nt*128) * FS_SH;
    Out = out;
  } else {
    const int rb = b - DN_SH_BLK;
    const int tile = rb % MAXT;
    nt = rb / MAXT;                              // 0..15
    if (tile >= n_rt[0]) return;
    rowbase = tile_rowbase[tile];
    valid   = tile_valid[tile];
    const int e = tile_e[tile];
    weighted = 1;
    A = h_routed; K = F_EXP;
    w_base = wb + O_WD + ((size_t)e*D_HID + nt*128) * F_EXP;
    Out = y_routed;
  }
  const size_t K2 = (size_t)K * 2;

  f32x4 acc[4][4];
  const f32x4 z = {0.f,0.f,0.f,0.f};
  #pragma unroll
  for (int m=0;m<4;m++)
    #pragma unroll
    for (int n=0;n<4;n++) acc[m][n]=z;

  const char* asrc[4];
  const int rowmax = rowbase + valid - 1;
  const int srccol = ((lane&7)<<4) ^ ((lane>>3)<<4);
  #pragma unroll
  for (int p=0;p<4;p++){
    const int row = wave*32 + p*8 + (lane>>3);
    int idx = rowbase + row;
    if (idx > rowmax) idx = rowmax;
    asrc[p] = (const char*)A + (size_t)idx * K2 + srccol;
  }
  const int brow0 = wave*16 + (lane>>3);
  const char* bsrc = (const char*)w_base + (size_t)brow0 * K2 + srccol;
  const size_t pstrB = 8 * K2;

  auto stage = [&](int bi, int kt){
    #pragma unroll
    for (int p=0;p<4;p++){
      __builtin_amdgcn_global_load_lds(
        (const AS1 void*)(asrc[p] + kt*128),
        (AS3 void*)(&As[bi][(wave*4 + p)*1024]), 16, 0, 0);
    }
    #pragma unroll
    for (int p=0;p<2;p++){
      __builtin_amdgcn_global_load_lds(
        (const AS1 void*)(bsrc + p*pstrB + kt*128),
        (AS3 void*)(&Bs[bi][(wave*2 + p)*1024]), 16, 0, 0);
    }
  };

  const int nK = K / 64;       // 44 or 22
  stage(0, 0);
  __syncthreads();
  int cur = 0;
  for (int kt = 0; kt < nK; ++kt){
    if (kt + 1 < nK) stage(cur^1, kt+1);
    #pragma unroll
    for (int kk=0;kk<2;kk++){
      const int kb = kk*64 + ((lane >> 4) << 4);
      bf16x8 a[4], bb[4];
      #pragma unroll
      for (int m=0;m<4;m++){
        const int r = wr*64 + m*16 + (lane & 15);
        a[m] = *(const bf16x8*)(&As[cur][r*128 + (kb ^ ((r & 7) << 4))]);
      }
      #pragma unroll
      for (int n=0;n<4;n++){
        const int r = wc*64 + n*16 + (lane & 15);
        bb[n] = *(const bf16x8*)(&Bs[cur][r*128 + (kb ^ ((r & 7) << 4))]);
      }
      #pragma unroll
      for (int m=0;m<4;m++)
        #pragma unroll
        for (int n=0;n<4;n++)
          acc[m][n] = __builtin_amdgcn_mfma_f32_16x16x32_bf16(a[m], bb[n], acc[m][n], 0,0,0);
    }
    __syncthreads();
    cur ^= 1;
  }

  const int colbase = nt*128 + wc*64;
  #pragma unroll
  for (int m=0;m<4;m++){
    #pragma unroll
    for (int r=0;r<4;r++){
      const int rr = wr*64 + m*16 + ((lane >> 4) << 2) + r;
      if (rr < valid){
        float w = 1.f;
        if (weighted) w = assign_w[rowbase + rr];
        float* orow = Out + (size_t)(rowbase + rr) * D_HID;
        #pragma unroll
        for (int n=0;n<4;n++){
          const int col = colbase + n*16 + (lane & 15);
          orow[col] = acc[m][n][r] * w;
        }
      }
    }
  }
}

// ---------------- combine: out += y[slot0] + y[slot1] ----------------
__global__ void combine_kernel(float* __restrict__ out, const float* __restrict__ y,
                               const int* __restrict__ token_slot){
  const int i  = blockIdx.x * blockDim.x + threadIdx.x;
  const int t  = i >> 9;
  const int r4 = i & 511;
  const int s0 = token_slot[t*2+0];
  const int s1 = token_slot[t*2+1];
  const float4 a = ((const float4*)(y + (size_t)s0 * D_HID))[r4];
  const float4 b = ((const float4*)(y + (size_t)s1 * D_HID))[r4];
  float4 o = ((float4*)out)[i];
  o.x += a.x + b.x; o.y += a.y + b.y; o.z += a.z + b.z; o.w += a.w + b.w;
  ((float4*)out)[i] = o;
}

extern "C" void kernel_launch(void* const* d_in, const int* in_sizes, int n_in,
                              void* d_out, int out_size, void* d_ws, size_t ws_size,
                              hipStream_t stream){
  const float* x   = (const float*)d_in[0];
  const float* Wr  = (const float*)d_in[1];
  const float* Wg  = (const float*)d_in[2];
  const float* Wu  = (const float*)d_in[3];
  const float* Wd  = (const float*)d_in[4];
  const float* Wsg = (const float*)d_in[5];
  const float* Wsu = (const float*)d_in[6];
  const float* Wsd = (const float*)d_in[7];
  float* out = (float*)d_out;
  (void)in_sizes; (void)n_in; (void)out_size; (void)ws_size;

  char* ws = (char*)d_ws;
  size_t off = 0;
  auto alloc = [&](size_t bytes)->char*{
    char* p = ws + off; off += (bytes + 255) & ~(size_t)255; return p;
  };

  unsigned short* wb       = (unsigned short*)alloc((size_t)W_TOT * 2);
  unsigned short* xb       = (unsigned short*)alloc((size_t)T_TOK * D_HID * 2);
  unsigned short* h_shared = (unsigned short*)alloc((size_t)T_TOK * FS_SH * 2);
  unsigned short* h_routed = (unsigned short*)alloc((size_t)T_TOK * 2 * F_EXP * 2);
  float*          y_routed = (float*)alloc((size_t)T_TOK * 2 * D_HID * 4);
  int*   topk_e       = (int*)alloc(T_TOK*2*sizeof(int));
  float* topk_w       = (float*)alloc(T_TOK*2*sizeof(float));
  int*   cnt          = (int*)alloc(E_NUM*sizeof(int));
  int*   offs         = (int*)alloc(E_NUM*sizeof(int));
  int*   assign_token = (int*)alloc(T_TOK*2*sizeof(int));
  float* assign_w     = (float*)alloc(T_TOK*2*sizeof(float));
  int*   token_slot   = (int*)alloc(T_TOK*2*sizeof(int));
  int*   tile_rowbase = (int*)alloc(MAXT*sizeof(int));
  int*   tile_e       = (int*)alloc(MAXT*sizeof(int));
  int*   tile_valid   = (int*)alloc(MAXT*sizeof(int));
  int*   n_rt         = (int*)alloc(sizeof(int));

  convert_x_kernel<<<(T_TOK*D_HID/4)/256, 256, 0, stream>>>(x, xb);
  router_kernel<<<T_TOK, 64, 0, stream>>>(x, Wr, topk_e, topk_w);
  build_lists_kernel<<<1, 1024, 0, stream>>>(topk_e, topk_w, cnt, offs,
      assign_token, assign_w, token_slot, tile_rowbase, tile_e, tile_valid, n_rt);
  convert_w_kernel<<<W_TOT/8/256, 256, 0, stream>>>(Wsg, Wsu, Wg, Wu, Wsd, Wd, wb);

  gateup_fused<<<GU_SH_BLK + MAXT*(F_EXP/128), 512, 0, stream>>>(
      xb, wb, h_shared, h_routed, tile_rowbase, tile_e, tile_valid, n_rt, assign_token);
  down_fused<<<DN_SH_BLK + MAXT*(D_HID/128), 512, 0, stream>>>(
      h_shared, h_routed, wb, out, y_routed, tile_rowbase, tile_e, tile_valid, n_rt, assign_w);

  combine_kernel<<<(T_TOK*D_HID/4)/256, 256, 0, stream>>>(out, y_routed, token_slot);
}

// Round 5
// 387.238 us; speedup vs baseline: 3.1842x; 1.0673x over previous
//
#include <hip/hip_runtime.h>
#include <hip/hip_bf16.h>

#define D_HID 2048
#define F_EXP 1408
#define E_NUM 8
#define FS_SH 2816
#define T_TOK 2048

// bf16 element offsets inside the converted-weight block wb
#define O_WSG 0
#define O_WSU 5767168
#define O_WG  11534336
#define O_WU  34603008
#define O_WSD 57671680
#define O_WD  63438848
#define W_TOT 86507520

#define MAXT 24          // max routed 256-row tiles (sum ceil(cnt_e/256) <= 23)
#define GU_SH_BLK 176    // shared gateup: 22 ntiles * 8 mtiles
#define DN_SH_BLK 128    // shared down:   16 ntiles * 8 mtiles

typedef __attribute__((ext_vector_type(8))) short bf16x8;
typedef __attribute__((ext_vector_type(4))) float f32x4;
typedef __attribute__((ext_vector_type(4))) unsigned short u16x4;

#define AS1 __attribute__((address_space(1)))
#define AS3 __attribute__((address_space(3)))

__device__ __forceinline__ unsigned short f2bf(float f){
  unsigned u = __float_as_uint(f);
  u += 0x7fffu + ((u >> 16) & 1u);          // RNE
  return (unsigned short)(u >> 16);
}

// ---------------- x fp32 -> bf16 ----------------
__global__ void convert_x_kernel(const float* __restrict__ x, unsigned short* __restrict__ xb){
  const int i = blockIdx.x * blockDim.x + threadIdx.x;
  float4 v = ((const float4*)x)[i];
  u16x4 h;
  h[0]=f2bf(v.x); h[1]=f2bf(v.y); h[2]=f2bf(v.z); h[3]=f2bf(v.w);
  ((u16x4*)xb)[i] = h;
}

// ---------------- all weights fp32 -> bf16 (contiguous wb) ----------------
__global__ __launch_bounds__(256) void convert_w_kernel(
    const float* __restrict__ Wsg, const float* __restrict__ Wsu,
    const float* __restrict__ Wg,  const float* __restrict__ Wu,
    const float* __restrict__ Wsd, const float* __restrict__ Wd,
    unsigned short* __restrict__ dst)
{
  const long e0 = ((long)blockIdx.x * 256 + threadIdx.x) * 8;
  const float* src; long lo;
  if      (e0 < (long)O_WSU){ src = Wsg; lo = e0 - O_WSG; }
  else if (e0 < (long)O_WG ){ src = Wsu; lo = e0 - O_WSU; }
  else if (e0 < (long)O_WU ){ src = Wg;  lo = e0 - O_WG;  }
  else if (e0 < (long)O_WSD){ src = Wu;  lo = e0 - O_WU;  }
  else if (e0 < (long)O_WD ){ src = Wsd; lo = e0 - O_WSD; }
  else                      { src = Wd;  lo = e0 - O_WD;  }
  const float4 a = ((const float4*)(src + lo))[0];
  const float4 b = ((const float4*)(src + lo))[1];
  u16x4 h0, h1;
  h0[0]=f2bf(a.x); h0[1]=f2bf(a.y); h0[2]=f2bf(a.z); h0[3]=f2bf(a.w);
  h1[0]=f2bf(b.x); h1[1]=f2bf(b.y); h1[2]=f2bf(b.z); h1[3]=f2bf(b.w);
  ((u16x4*)(dst + e0))[0] = h0;
  ((u16x4*)(dst + e0))[1] = h1;
}

// ---------------- router: logits, softmax, top-2 ----------------
__global__ __launch_bounds__(64) void router_kernel(const float* __restrict__ x,
                                                    const float* __restrict__ Wr,
                                                    int* __restrict__ topk_e,
                                                    float* __restrict__ topk_w){
  const int t = blockIdx.x;
  const int lane = threadIdx.x;
  const float* xt = x + (size_t)t * D_HID;
  float acc[E_NUM];
  #pragma unroll
  for (int e=0;e<E_NUM;e++) acc[e]=0.f;
  for (int d=lane; d<D_HID; d+=64){
    const float xv = xt[d];
    #pragma unroll
    for (int e=0;e<E_NUM;e++) acc[e] += xv * Wr[e*D_HID + d];
  }
  #pragma unroll
  for (int e=0;e<E_NUM;e++){
    #pragma unroll
    for (int off=32; off>0; off>>=1) acc[e] += __shfl_xor(acc[e], off);
  }
  if (lane==0){
    float m = acc[0];
    #pragma unroll
    for (int e=1;e<E_NUM;e++) m = fmaxf(m, acc[e]);
    float p[E_NUM]; float s = 0.f;
    #pragma unroll
    for (int e=0;e<E_NUM;e++){ p[e] = expf(acc[e]-m); s += p[e]; }
    const float inv = 1.f/s;
    int i0=0; float b0=p[0];
    #pragma unroll
    for (int e=1;e<E_NUM;e++) if (p[e] > b0){ b0=p[e]; i0=e; }
    int i1=-1; float b1=-1.f;
    #pragma unroll
    for (int e=0;e<E_NUM;e++) if (e!=i0 && p[e] > b1){ b1=p[e]; i1=e; }
    topk_e[t*2+0]=i0; topk_e[t*2+1]=i1;
    topk_w[t*2+0]=b0*inv; topk_w[t*2+1]=b1*inv;
  }
}

// ---------------- deterministic expert-grouped list build + tile records ----------------
__global__ __launch_bounds__(1024) void build_lists_kernel(
    const int* __restrict__ topk_e, const float* __restrict__ topk_w,
    int* __restrict__ cnt, int* __restrict__ offs,
    int* __restrict__ assign_token, float* __restrict__ assign_w,
    int* __restrict__ token_slot,
    int* __restrict__ tile_rowbase, int* __restrict__ tile_e,
    int* __restrict__ tile_valid, int* __restrict__ n_rt)
{
  const int tid  = threadIdx.x;
  const int lane = tid & 63;
  const int wv   = tid >> 6;                 // 16 waves
  __shared__ int wsum[E_NUM][16];
  __shared__ int tot_s[E_NUM];
  __shared__ int offs_s[E_NUM];

  int   e_loc[4];
  float w_loc[4];
  #pragma unroll
  for (int j=0;j<4;j++){ e_loc[j]=topk_e[tid*4+j]; w_loc[j]=topk_w[tid*4+j]; }

  int c[E_NUM];
  #pragma unroll
  for (int e=0;e<E_NUM;e++){
    int s = 0;
    #pragma unroll
    for (int j=0;j<4;j++) s += (e_loc[j]==e) ? 1 : 0;
    c[e] = s;
  }
  int pre[E_NUM];
  #pragma unroll
  for (int e=0;e<E_NUM;e++){
    int v = c[e];
    #pragma unroll
    for (int off=1; off<64; off<<=1){
      int t = __shfl_up(v, off);
      if (lane >= off) v += t;
    }
    if (lane==63) wsum[e][wv] = v;
    pre[e] = v - c[e];
  }
  __syncthreads();
  if (tid < E_NUM){
    int s = 0;
    #pragma unroll
    for (int w=0; w<16; w++){ int t = wsum[tid][w]; wsum[tid][w] = s; s += t; }
    tot_s[tid] = s;
    cnt[tid]   = s;
  }
  __syncthreads();
  if (tid == 0){
    int s = 0;
    #pragma unroll
    for (int e=0;e<E_NUM;e++){ offs_s[e] = s; offs[e] = s; s += tot_s[e]; }
    // compacted 256-row tile records for routed GEMMs
    int ntl = 0;
    for (int e=0;e<E_NUM;e++){
      for (int r=0; r<tot_s[e]; r+=256){
        tile_rowbase[ntl] = offs_s[e] + r;
        tile_e[ntl]       = e;
        int v = tot_s[e] - r; if (v > 256) v = 256;
        tile_valid[ntl]   = v;
        ntl++;
      }
    }
    n_rt[0] = ntl;
    for (int i=ntl;i<MAXT;i++){ tile_rowbase[i]=0; tile_e[i]=0; tile_valid[i]=0; }
  }
  __syncthreads();
  int local[E_NUM];
  #pragma unroll
  for (int e=0;e<E_NUM;e++) local[e]=0;
  #pragma unroll
  for (int j=0;j<4;j++){
    const int e = e_loc[j];
    int pos = 0;
    #pragma unroll
    for (int ee=0; ee<E_NUM; ee++)
      if (e == ee) pos = offs_s[ee] + wsum[ee][wv] + pre[ee] + local[ee];
    #pragma unroll
    for (int ee=0; ee<E_NUM; ee++) local[ee] += (e == ee) ? 1 : 0;
    const int entry = tid*4 + j;
    assign_token[pos] = entry >> 1;
    assign_w[pos]     = w_loc[j];
    token_slot[entry] = pos;
  }
}

// ================= fused gate+up GEMM, 2-phase dbuf + counted vmcnt =================
// 512 thr / 8 waves (4M x 2N), BM=256, BN=128, BK=64. LDS = 128 KB.
__global__ __launch_bounds__(512,1) void gateup_fused(
    const unsigned short* __restrict__ xb,
    const unsigned short* __restrict__ wb,
    unsigned short* __restrict__ h_shared,
    unsigned short* __restrict__ h_routed,
    const int* __restrict__ tile_rowbase, const int* __restrict__ tile_e,
    const int* __restrict__ tile_valid, const int* __restrict__ n_rt,
    const int* __restrict__ assign_token)
{
  __shared__ __align__(16) char As[2][256*128];   // 64 KB
  __shared__ __align__(16) char Bg[2][128*128];   // 32 KB
  __shared__ __align__(16) char Bu[2][128*128];   // 32 KB

  const int tid  = threadIdx.x;
  const int lane = tid & 63;
  const int wave = tid >> 6;       // 0..7
  const int wr = wave >> 1;        // 0..3
  const int wc = wave & 1;         // 0..1
  const int b = blockIdx.x;

  int nt, rowbase, valid, gather;
  const unsigned short *wg_base, *wu_base;
  unsigned short* H; int N;
  if (b < GU_SH_BLK){
    nt = b >> 3; const int mtile = b & 7;       // 8 consecutive blocks share a weight panel
    rowbase = mtile*256; valid = 256; gather = 0;
    wg_base = wb + O_WSG + (size_t)(nt*128) * D_HID;
    wu_base = wb + O_WSU + (size_t)(nt*128) * D_HID;
    H = h_shared; N = FS_SH;
  } else {
    const int rb = b - GU_SH_BLK;
    const int tile = rb % MAXT;
    nt = rb / MAXT;                              // 0..10
    if (tile >= n_rt[0]) return;
    rowbase = tile_rowbase[tile];
    valid   = tile_valid[tile];
    const int e = tile_e[tile];
    gather = 1;
    wg_base = wb + O_WG + ((size_t)e*F_EXP + nt*128) * D_HID;
    wu_base = wb + O_WU + ((size_t)e*F_EXP + nt*128) * D_HID;
    H = h_routed; N = F_EXP;
  }

  f32x4 accg[4][4], accu[4][4];
  const f32x4 z = {0.f,0.f,0.f,0.f};
  #pragma unroll
  for (int m=0;m<4;m++)
    #pragma unroll
    for (int n=0;n<4;n++){ accg[m][n]=z; accu[m][n]=z; }

  // A sources: 4 chunks/wave (1 KB each), pre-swizzled source column
  const char* asrc[4];
  const int rowmax = rowbase + valid - 1;
  const int srccol = ((lane&7)<<4) ^ ((lane>>3)<<4);
  #pragma unroll
  for (int p=0;p<4;p++){
    const int row = wave*32 + p*8 + (lane>>3);
    int idx = rowbase + row;
    if (idx > rowmax) idx = rowmax;
    const size_t grow = gather ? (size_t)assign_token[idx] : (size_t)idx;
    asrc[p] = (const char*)(xb + grow * (size_t)D_HID) + srccol;
  }
  // B sources: 2 chunks/wave each
  const int brow0 = wave*16 + (lane>>3);
  const char* gsrc = (const char*)(wg_base + (size_t)brow0 * D_HID) + srccol;
  const char* usrc = (const char*)(wu_base + (size_t)brow0 * D_HID) + srccol;
  const int pstrB = 8 * D_HID * 2;

  auto stage = [&](int bi, int kt){
    #pragma unroll
    for (int p=0;p<4;p++){
      __builtin_amdgcn_global_load_lds(
        (const AS1 void*)(asrc[p] + kt*128),
        (AS3 void*)(&As[bi][(wave*4 + p)*1024]), 16, 0, 0);
    }
    #pragma unroll
    for (int p=0;p<2;p++){
      __builtin_amdgcn_global_load_lds(
        (const AS1 void*)(gsrc + p*pstrB + kt*128),
        (AS3 void*)(&Bg[bi][(wave*2 + p)*1024]), 16, 0, 0);
      __builtin_amdgcn_global_load_lds(
        (const AS1 void*)(usrc + p*pstrB + kt*128),
        (AS3 void*)(&Bu[bi][(wave*2 + p)*1024]), 16, 0, 0);
    }
  };

  const int nK = D_HID / 64;   // 32
  stage(0, 0);                 // 8 loads in flight
  int cur = 0;
  for (int kt = 0; kt < nK; ++kt){
    if (kt + 1 < nK){
      stage(cur^1, kt+1);      // +8 loads: 16 outstanding
      // wait for cur's 8 (oldest); next's 8 stay in flight ACROSS the barrier (T4)
      asm volatile("s_waitcnt vmcnt(8)\n\ts_barrier" ::: "memory");
    } else {
      asm volatile("s_waitcnt vmcnt(0)\n\ts_barrier" ::: "memory");
    }
    #pragma unroll
    for (int kk=0;kk<2;kk++){
      const int kb = kk*64 + ((lane >> 4) << 4);
      bf16x8 a[4], bg[4], bu[4];
      #pragma unroll
      for (int m=0;m<4;m++){
        const int r = wr*64 + m*16 + (lane & 15);
        a[m] = *(const bf16x8*)(&As[cur][r*128 + (kb ^ ((r & 7) << 4))]);
      }
      #pragma unroll
      for (int n=0;n<4;n++){
        const int r = wc*64 + n*16 + (lane & 15);
        const int ofs = r*128 + (kb ^ ((r & 7) << 4));
        bg[n] = *(const bf16x8*)(&Bg[cur][ofs]);
        bu[n] = *(const bf16x8*)(&Bu[cur][ofs]);
      }
      #pragma unroll
      for (int m=0;m<4;m++)
        #pragma unroll
        for (int n=0;n<4;n++){
          accg[m][n] = __builtin_amdgcn_mfma_f32_16x16x32_bf16(a[m], bg[n], accg[m][n], 0,0,0);
          accu[m][n] = __builtin_amdgcn_mfma_f32_16x16x32_bf16(a[m], bu[n], accu[m][n], 0,0,0);
        }
    }
    // all waves done reading buf cur before its next overwrite
    asm volatile("s_barrier" ::: "memory");
    cur ^= 1;
  }

  const int colbase = nt*128 + wc*64;
  #pragma unroll
  for (int m=0;m<4;m++){
    #pragma unroll
    for (int r=0;r<4;r++){
      const int rr = wr*64 + m*16 + ((lane >> 4) << 2) + r;
      if (rr < valid){
        unsigned short* orow = H + (size_t)(rowbase + rr) * N;
        #pragma unroll
        for (int n=0;n<4;n++){
          const int col = colbase + n*16 + (lane & 15);
          const float g = accg[m][n][r];
          const float u = accu[m][n][r];
          const float h = (g / (1.f + __expf(-g))) * u;
          orow[col] = f2bf(h);
        }
      }
    }
  }
}

// ================= fused down GEMM, 2-phase dbuf + counted vmcnt =================
__global__ __launch_bounds__(512,1) void down_fused(
    const unsigned short* __restrict__ h_shared,
    const unsigned short* __restrict__ h_routed,
    const unsigned short* __restrict__ wb,
    float* __restrict__ out, float* __restrict__ y_routed,
    const int* __restrict__ tile_rowbase, const int* __restrict__ tile_e,
    const int* __restrict__ tile_valid, const int* __restrict__ n_rt,
    const float* __restrict__ assign_w)
{
  __shared__ __align__(16) char As[2][256*128];   // 64 KB
  __shared__ __align__(16) char Bs[2][128*128];   // 32 KB

  const int tid  = threadIdx.x;
  const int lane = tid & 63;
  const int wave = tid >> 6;
  const int wr = wave >> 1, wc = wave & 1;
  const int b = blockIdx.x;

  int nt, rowbase, valid, weighted, K;
  const unsigned short *A, *w_base;
  float* Out;
  if (b < DN_SH_BLK){
    nt = b >> 3; const int mtile = b & 7;
    rowbase = mtile*256; valid = 256; weighted = 0;
    A = h_shared; K = FS_SH;
    w_base = wb + O_WSD + (size_t)(nt*128) * FS_SH;
    Out = out;
  } else {
    const int rb = b - DN_SH_BLK;
    const int tile = rb % MAXT;
    nt = rb / MAXT;                              // 0..15
    if (tile >= n_rt[0]) return;
    rowbase = tile_rowbase[tile];
    valid   = tile_valid[tile];
    const int e = tile_e[tile];
    weighted = 1;
    A = h_routed; K = F_EXP;
    w_base = wb + O_WD + ((size_t)e*D_HID + nt*128) * F_EXP;
    Out = y_routed;
  }
  const size_t K2 = (size_t)K * 2;

  f32x4 acc[4][4];
  const f32x4 z = {0.f,0.f,0.f,0.f};
  #pragma unroll
  for (int m=0;m<4;m++)
    #pragma unroll
    for (int n=0;n<4;n++) acc[m][n]=z;

  const char* asrc[4];
  const int rowmax = rowbase + valid - 1;
  const int srccol = ((lane&7)<<4) ^ ((lane>>3)<<4);
  #pragma unroll
  for (int p=0;p<4;p++){
    const int row = wave*32 + p*8 + (lane>>3);
    int idx = rowbase + row;
    if (idx > rowmax) idx = rowmax;
    asrc[p] = (const char*)A + (size_t)idx * K2 + srccol;
  }
  const int brow0 = wave*16 + (lane>>3);
  const char* bsrc = (const char*)w_base + (size_t)brow0 * K2 + srccol;
  const size_t pstrB = 8 * K2;

  auto stage = [&](int bi, int kt){
    #pragma unroll
    for (int p=0;p<4;p++){
      __builtin_amdgcn_global_load_lds(
        (const AS1 void*)(asrc[p] + kt*128),
        (AS3 void*)(&As[bi][(wave*4 + p)*1024]), 16, 0, 0);
    }
    #pragma unroll
    for (int p=0;p<2;p++){
      __builtin_amdgcn_global_load_lds(
        (const AS1 void*)(bsrc + p*pstrB + kt*128),
        (AS3 void*)(&Bs[bi][(wave*2 + p)*1024]), 16, 0, 0);
    }
  };

  const int nK = K / 64;       // 44 or 22
  stage(0, 0);                 // 6 loads in flight
  int cur = 0;
  for (int kt = 0; kt < nK; ++kt){
    if (kt + 1 < nK){
      stage(cur^1, kt+1);      // +6: 12 outstanding
      asm volatile("s_waitcnt vmcnt(6)\n\ts_barrier" ::: "memory");
    } else {
      asm volatile("s_waitcnt vmcnt(0)\n\ts_barrier" ::: "memory");
    }
    #pragma unroll
    for (int kk=0;kk<2;kk++){
      const int kb = kk*64 + ((lane >> 4) << 4);
      bf16x8 a[4], bb[4];
      #pragma unroll
      for (int m=0;m<4;m++){
        const int r = wr*64 + m*16 + (lane & 15);
        a[m] = *(const bf16x8*)(&As[cur][r*128 + (kb ^ ((r & 7) << 4))]);
      }
      #pragma unroll
      for (int n=0;n<4;n++){
        const int r = wc*64 + n*16 + (lane & 15);
        bb[n] = *(const bf16x8*)(&Bs[cur][r*128 + (kb ^ ((r & 7) << 4))]);
      }
      #pragma unroll
      for (int m=0;m<4;m++)
        #pragma unroll
        for (int n=0;n<4;n++)
          acc[m][n] = __builtin_amdgcn_mfma_f32_16x16x32_bf16(a[m], bb[n], acc[m][n], 0,0,0);
    }
    asm volatile("s_barrier" ::: "memory");
    cur ^= 1;
  }

  const int colbase = nt*128 + wc*64;
  #pragma unroll
  for (int m=0;m<4;m++){
    #pragma unroll
    for (int r=0;r<4;r++){
      const int rr = wr*64 + m*16 + ((lane >> 4) << 2) + r;
      if (rr < valid){
        float w = 1.f;
        if (weighted) w = assign_w[rowbase + rr];
        float* orow = Out + (size_t)(rowbase + rr) * D_HID;
        #pragma unroll
        for (int n=0;n<4;n++){
          const int col = colbase + n*16 + (lane & 15);
          orow[col] = acc[m][n][r] * w;
        }
      }
    }
  }
}

// ---------------- combine: out += y[slot0] + y[slot1] ----------------
__global__ void combine_kernel(float* __restrict__ out, const float* __restrict__ y,
                               const int* __restrict__ token_slot){
  const int i  = blockIdx.x * blockDim.x + threadIdx.x;
  const int t  = i >> 9;
  const int r4 = i & 511;
  const int s0 = token_slot[t*2+0];
  const int s1 = token_slot[t*2+1];
  const float4 a = ((const float4*)(y + (size_t)s0 * D_HID))[r4];
  const float4 b = ((const float4*)(y + (size_t)s1 * D_HID))[r4];
  float4 o = ((float4*)out)[i];
  o.x += a.x + b.x; o.y += a.y + b.y; o.z += a.z + b.z; o.w += a.w + b.w;
  ((float4*)out)[i] = o;
}

extern "C" void kernel_launch(void* const* d_in, const int* in_sizes, int n_in,
                              void* d_out, int out_size, void* d_ws, size_t ws_size,
                              hipStream_t stream){
  const float* x   = (const float*)d_in[0];
  const float* Wr  = (const float*)d_in[1];
  const float* Wg  = (const float*)d_in[2];
  const float* Wu  = (const float*)d_in[3];
  const float* Wd  = (const float*)d_in[4];
  const float* Wsg = (const float*)d_in[5];
  const float* Wsu = (const float*)d_in[6];
  const float* Wsd = (const float*)d_in[7];
  float* out = (float*)d_out;
  (void)in_sizes; (void)n_in; (void)out_size; (void)ws_size;

  char* ws = (char*)d_ws;
  size_t off = 0;
  auto alloc = [&](size_t bytes)->char*{
    char* p = ws + off; off += (bytes + 255) & ~(size_t)255; return p;
  };

  unsigned short* wb       = (unsigned short*)alloc((size_t)W_TOT * 2);
  unsigned short* xb       = (unsigned short*)alloc((size_t)T_TOK * D_HID * 2);
  unsigned short* h_shared = (unsigned short*)alloc((size_t)T_TOK * FS_SH * 2);
  unsigned short* h_routed = (unsigned short*)alloc((size_t)T_TOK * 2 * F_EXP * 2);
  float*          y_routed = (float*)alloc((size_t)T_TOK * 2 * D_HID * 4);
  int*   topk_e       = (int*)alloc(T_TOK*2*sizeof(int));
  float* topk_w       = (float*)alloc(T_TOK*2*sizeof(float));
  int*   cnt          = (int*)alloc(E_NUM*sizeof(int));
  int*   offs         = (int*)alloc(E_NUM*sizeof(int));
  int*   assign_token = (int*)alloc(T_TOK*2*sizeof(int));
  float* assign_w     = (float*)alloc(T_TOK*2*sizeof(float));
  int*   token_slot   = (int*)alloc(T_TOK*2*sizeof(int));
  int*   tile_rowbase = (int*)alloc(MAXT*sizeof(int));
  int*   tile_e       = (int*)alloc(MAXT*sizeof(int));
  int*   tile_valid   = (int*)alloc(MAXT*sizeof(int));
  int*   n_rt         = (int*)alloc(sizeof(int));

  convert_x_kernel<<<(T_TOK*D_HID/4)/256, 256, 0, stream>>>(x, xb);
  router_kernel<<<T_TOK, 64, 0, stream>>>(x, Wr, topk_e, topk_w);
  build_lists_kernel<<<1, 1024, 0, stream>>>(topk_e, topk_w, cnt, offs,
      assign_token, assign_w, token_slot, tile_rowbase, tile_e, tile_valid, n_rt);
  convert_w_kernel<<<W_TOT/8/256, 256, 0, stream>>>(Wsg, Wsu, Wg, Wu, Wsd, Wd, wb);

  gateup_fused<<<GU_SH_BLK + MAXT*(F_EXP/128), 512, 0, stream>>>(
      xb, wb, h_shared, h_routed, tile_rowbase, tile_e, tile_valid, n_rt, assign_token);
  down_fused<<<DN_SH_BLK + MAXT*(D_HID/128), 512, 0, stream>>>(
      h_shared, h_routed, wb, out, y_routed, tile_rowbase, tile_e, tile_valid, n_rt, assign_w);

  combine_kernel<<<(T_TOK*D_HID/4)/256, 256, 0, stream>>>(out, y_routed, token_slot);
}